// Round 6
// baseline (903.358 us; speedup 1.0000x reference)
//
#include <hip/hip_runtime.h>
#include <hip/hip_bf16.h>

#define N_GRAPHS 4096
#define N_ELE 16384
#define EPS 1e-5f

// ws layout (f32 words)
#define A_TAB_OFF 0               // 4096*64 f32 atomic sums
#define A_CNT_OFF 262144          // 4096
#define E_TAB_OFF 266240          // 16384*64
#define E_CNT_OFF 1314816         // 16384
#define STAT_OFF  1331200         // 32 copies * (256 sums + 256 sqs)
#define ZPAD_OFF  1347584         // (unused this round)
#define ZERO_WORDS 1347588        // memset range: everything above
#define A_TABH_OFF 1347600        // 4096*64 bf16 = 131072 words
#define E_TABH_OFF 1478672        // 16384*64 bf16 = 524288 words
#define W1PK_OFF  2002960         // 96 frags * 64 lanes * 8 bf16 = 24576 words
#define FCPK_OFF  2027536         // 64 frags * 64 lanes * 8 bf16 = 16384 words
#define SCALE_OFF 2043920         // 256
#define SHIFT_OFF 2044176         // 256
#define WS_WORDS  2044432         // ~8.2 MB

typedef __attribute__((ext_vector_type(8))) short bf16x8;
typedef __attribute__((ext_vector_type(4))) float f32x4;

__device__ __forceinline__ float bf2f(unsigned s) { return __uint_as_float(s << 16); }
__device__ __forceinline__ unsigned f2bf(float f) {
  unsigned u = __float_as_uint(f);
  return (u + 0x7fffu + ((u >> 16) & 1u)) >> 16;  // RNE
}
__device__ __forceinline__ unsigned pkbf(float a, float b) {
  union { __hip_bfloat16 h; unsigned short u; } ca, cb;
  ca.h = __float2bfloat16(a); cb.h = __float2bfloat16(b);
  return (unsigned)ca.u | ((unsigned)cb.u << 16);
}
__device__ __forceinline__ bf16x8 cvt8(float4 a, float4 b) {
  union { bf16x8 v; unsigned u[4]; } r;
  r.u[0] = pkbf(a.x, a.y); r.u[1] = pkbf(a.z, a.w);
  r.u[2] = pkbf(b.x, b.y); r.u[3] = pkbf(b.z, b.w);
  return r.v;
}

// ---------------- K0: pack W1,W2 (96-frag stream) and fcW (64-frag stream) ----------------
// k_gemm B stream order (seq 0..95):
//   seq<32:  zkb=seq>>3 (0..3), L=(zkb>=2), ct=seq&7
//   seq>=32: o=seq-32; zkb=4+(o>>4); L=(o>>3)&1; ct=o&7
// frag elem (lane,j): col = ct*16+(lane&15), kW = (zkb - (zkb>=2?2:0))*32 + (lane>>4)*8 + j
__global__ void k_prep(const float* __restrict__ W1, const float* __restrict__ W2,
                       const float* __restrict__ fcW, float* __restrict__ ws) {
  int tid = blockIdx.x * 512 + threadIdx.x;
  if (tid < 49152) {
    unsigned short* wpk = (unsigned short*)(ws + W1PK_OFF);
    int ord = tid >> 9, lane = (tid >> 3) & 63, j = tid & 7;
    int zkb, L, ct;
    if (ord < 32) { zkb = ord >> 3; L = (zkb >= 2); ct = ord & 7; }
    else { int o = ord - 32; zkb = 4 + (o >> 4); L = (o >> 3) & 1; ct = o & 7; }
    int kW = (zkb - (zkb >= 2 ? 2 : 0)) * 32 + ((lane >> 4) << 3) + j;
    const float* W = L ? W2 : W1;
    wpk[tid] = (unsigned short)f2bf(W[(ct * 16 + (lane & 15)) * 192 + kW]);
  } else {
    int idx = tid - 49152;  // 0..32767
    unsigned short* fpk = (unsigned short*)(ws + FCPK_OFF);
    int ord = idx >> 9, lane = (idx >> 3) & 63, j = idx & 7;
    int kb = ord >> 3, ct = ord & 7;
    fpk[idx] = (unsigned short)f2bf(fcW[(ct * 16 + (lane & 15)) * 256 + kb * 32 + ((lane >> 4) << 3) + j]);
  }
}

// ---------------- K1: segment sums ----------------
__global__ void k_seg(const float* __restrict__ x, const int* __restrict__ aidx,
                      const int* __restrict__ eidx, float* __restrict__ ws, int N) {
  float* A_tab = ws + A_TAB_OFF; float* A_cnt = ws + A_CNT_OFF;
  float* E_tab = ws + E_TAB_OFF; float* E_cnt = ws + E_CNT_OFF;
  int t = threadIdx.x;
  int c = t & 63, p = (t >> 6) & 1, s = t >> 7;
  int r0 = blockIdx.x * 256;
  int rend = min(r0 + 256, N);
  if (p == 0) {
    float acc = 0.f, cnt = 0.f; int cur = -1;
    for (int r = r0 + s; r < rend; r += 2) {
      int a = aidx[r];
      float v = x[(size_t)r * 128 + c];
      if (a != cur) {
        if (cur >= 0) { atomicAdd(&A_tab[cur * 64 + c], acc); if (c == 0) atomicAdd(&A_cnt[cur], cnt); }
        cur = a; acc = v; cnt = 1.f;
      } else { acc += v; cnt += 1.f; }
    }
    if (cur >= 0) { atomicAdd(&A_tab[cur * 64 + c], acc); if (c == 0) atomicAdd(&A_cnt[cur], cnt); }
  } else {
    for (int r = r0 + s; r < rend; r += 2) {
      int e = eidx[r];
      float v = x[(size_t)r * 128 + 64 + c];
      atomicAdd(&E_tab[e * 64 + c], v);
      if (c == 0) atomicAdd(&E_cnt[e], 1.f);
    }
  }
}

// ---------------- K2: mean + relu -> bf16 tables ----------------
__global__ void k_fin(float* __restrict__ ws) {
  int i = blockIdx.x * 256 + threadIdx.x;
  unsigned* w32 = (unsigned*)ws;
  if (i < 131072) {
    int e = 2 * i;
    float cnt = fmaxf(ws[A_CNT_OFF + (e >> 6)], 1.f);
    float v0 = fmaxf(ws[A_TAB_OFF + e] / cnt, 0.f);
    float v1 = fmaxf(ws[A_TAB_OFF + e + 1] / cnt, 0.f);
    w32[A_TABH_OFF + i] = f2bf(v0) | (f2bf(v1) << 16);
  }
  if (i < 524288) {
    int e = 2 * i;
    float cnt = fmaxf(ws[E_CNT_OFF + (e >> 6)], 1.f);
    float v0 = fmaxf(ws[E_TAB_OFF + e] / cnt, 0.f);
    float v1 = fmaxf(ws[E_TAB_OFF + e + 1] / cnt, 0.f);
    w32[E_TABH_OFF + i] = f2bf(v0) | (f2bf(v1) << 16);
  }
}

// ---------------- K3: wave-independent MFMA dual GEMM (16 rows x 256 cols per wave) ----------------
// No staging LDS, no mid-kernel barriers. A-frags gathered to regs; B streamed from packed ws.
// Per-wave 8KB LDS epilogue transpose (wave-local lgkmcnt ordering). One final barrier for BN stats.
#define MM8(A, ACC, S) { _Pragma("unroll") \
  for (int ct = 0; ct < 8; ++ct) ACC[ct] = __builtin_amdgcn_mfma_f32_16x16x32_bf16(A, Bp[(S + ct) * 64], ACC[ct], 0, 0, 0); }

__global__ __launch_bounds__(256) void k_gemm(
    const float* __restrict__ rdf, const float* __restrict__ bdf,
    const int* __restrict__ aidx, const int* __restrict__ eidx,
    float* __restrict__ ws, unsigned* __restrict__ outp, int N) {
  __shared__ __align__(16) char smem[40960];   // 4 x 8KB transpose + 8KB stats
  const unsigned short* Atabh = (const unsigned short*)(ws + A_TABH_OFF);
  const unsigned short* Etabh = (const unsigned short*)(ws + E_TABH_OFF);
  int t = threadIdx.x, l = t & 63, w = t >> 6;
  int row0 = blockIdx.x * 64 + w * 16;
  int row = row0 + (l & 15);
  bool ok = row < N;
  int rowc = ok ? row : 0;
  int koff = (l >> 4) << 3;

  // ---- gather A-frags directly to registers ----
  int ia = aidx[rowc], ie = eidx[rowc];
  const float* r0 = rdf + (size_t)rowc * 64 + koff;
  const float* b0 = bdf + (size_t)rowc * 64 + koff;
  bf16x8 a0 = cvt8(*(const float4*)r0, *(const float4*)(r0 + 4));
  bf16x8 a1 = cvt8(*(const float4*)(r0 + 32), *(const float4*)(r0 + 36));
  bf16x8 a2 = cvt8(*(const float4*)b0, *(const float4*)(b0 + 4));
  bf16x8 a3 = cvt8(*(const float4*)(b0 + 32), *(const float4*)(b0 + 36));
  const char* pa = (const char*)(Atabh + (size_t)ia * 64 + koff);
  const char* pe = (const char*)(Etabh + (size_t)ie * 64 + koff);
  bf16x8 a4 = *(const bf16x8*)pa;
  bf16x8 a5 = *(const bf16x8*)(pa + 64);
  bf16x8 a6 = *(const bf16x8*)pe;
  bf16x8 a7 = *(const bf16x8*)(pe + 64);
  if (!ok) {
    bf16x8 z = (bf16x8){0,0,0,0,0,0,0,0};
    a0 = z; a1 = z; a2 = z; a3 = z; a4 = z; a5 = z; a6 = z; a7 = z;
  }

  // ---- MFMA: 96 ops, B streamed sequentially ----
  const bf16x8* Bp = (const bf16x8*)((const unsigned short*)(ws + W1PK_OFF) + (size_t)l * 8);
  f32x4 acc0[8], acc1[8];
  #pragma unroll
  for (int ct = 0; ct < 8; ++ct) { acc0[ct] = (f32x4){0.f,0.f,0.f,0.f}; acc1[ct] = (f32x4){0.f,0.f,0.f,0.f}; }
  MM8(a0, acc0, 0)  MM8(a1, acc0, 8)
  MM8(a2, acc1, 16) MM8(a3, acc1, 24)
  MM8(a4, acc0, 32) MM8(a4, acc1, 40)
  MM8(a5, acc0, 48) MM8(a5, acc1, 56)
  MM8(a6, acc0, 64) MM8(a6, acc1, 72)
  MM8(a7, acc0, 80) MM8(a7, acc1, 88)

  // ---- BN stat partials -> LDS (per wave) ----
  float* statf = (float*)(smem + 32768);
  #define STAT8(ACC, L) { _Pragma("unroll") for (int ct = 0; ct < 8; ++ct) { \
    f32x4 A_ = ACC[ct]; \
    float s_ = A_[0] + A_[1] + A_[2] + A_[3]; \
    float q_ = A_[0]*A_[0] + A_[1]*A_[1] + A_[2]*A_[2] + A_[3]*A_[3]; \
    s_ += __shfl_xor(s_, 16); s_ += __shfl_xor(s_, 32); \
    q_ += __shfl_xor(q_, 16); q_ += __shfl_xor(q_, 32); \
    if (l < 16) { int gc = L * 128 + ct * 16 + l; \
      statf[w * 512 + gc] = s_; statf[w * 512 + 256 + gc] = q_; } } }
  STAT8(acc0, 0)
  STAT8(acc1, 1)

  // ---- per-wave LDS transpose -> coalesced bf16 h store (row-major [N][256]) ----
  char* T = smem + w * 8192;   // [16 rows][512B], chunk swizzle cs = (ch&24)|((ch^row)&7)
  #define TWR(ACC, L) { _Pragma("unroll") for (int ct = 0; ct < 8; ++ct) { \
    _Pragma("unroll") for (int rr = 0; rr < 4; ++rr) { \
      unsigned ub = pkbf(ACC[ct][rr], 0.f) & 0xffffu; \
      unsigned pb = (unsigned)__shfl_xor((int)ub, 1); \
      if (!(l & 1)) { \
        int rowt = ((l >> 4) << 2) + rr; \
        int gc = L * 128 + ct * 16 + (l & 15); \
        int ch = gc >> 3; \
        int cs = (ch & 24) | ((ch ^ rowt) & 7); \
        *(unsigned*)(T + rowt * 512 + cs * 16 + ((gc >> 1) & 3) * 4) = ub | (pb << 16); } } } }
  TWR(acc0, 0)
  TWR(acc1, 1)
  asm volatile("s_waitcnt lgkmcnt(0)" ::: "memory");
  __builtin_amdgcn_sched_barrier(0);
  #pragma unroll
  for (int q = 0; q < 8; ++q) {
    int rowt = l >> 2, cl = ((l & 3) << 3) + q;
    int cs = (cl & 24) | ((cl ^ rowt) & 7);
    uint4 v = *(const uint4*)(T + rowt * 512 + cs * 16);
    int grow = row0 + rowt;
    if (grow < N) *(uint4*)((char*)outp + (size_t)grow * 512 + cl * 16) = v;
  }

  // ---- block stat reduce -> one atomic per col ----
  __syncthreads();
  float* stat = ws + STAT_OFF + (blockIdx.x & 31) * 512;
  #pragma unroll
  for (int u = 0; u < 2; ++u) {
    int c = t + u * 256;
    float r = statf[c] + statf[512 + c] + statf[1024 + c] + statf[1536 + c];
    atomicAdd(&stat[c], r);
  }
}

// ---------------- K4: BN finalize -> scale/shift ----------------
__global__ void k_bnfin(const float* __restrict__ g1, const float* __restrict__ b1,
                        const float* __restrict__ g2, const float* __restrict__ b2,
                        float* __restrict__ ws, int N) {
  int c = threadIdx.x;  // 256
  float s = 0.f, q = 0.f;
  for (int m = 0; m < 32; ++m) { s += ws[STAT_OFF + m * 512 + c]; q += ws[STAT_OFF + m * 512 + 256 + c]; }
  float inv = 1.f / (float)N;
  float mu = s * inv;
  float var = fmaxf(q * inv - mu * mu, 0.f);
  int lyr = c >> 7, cc = c & 127;
  float ga = lyr ? g2[cc] : g1[cc];
  float be = lyr ? b2[cc] : b1[cc];
  float sc = ga * rsqrtf(var + EPS);
  ws[SCALE_OFF + c] = sc;
  ws[SHIFT_OFF + c] = be - mu * sc;
}

// ---------------- K5: wave-independent fc GEMM, BN+residual+relu in-register (in-place) ----------------
__global__ __launch_bounds__(256) void k_fc(
    const float* __restrict__ x, const float* __restrict__ fcb,
    float* __restrict__ ws, float* __restrict__ out, int N) {
  __shared__ __align__(16) char smem[32768];   // 4 x 8KB transpose
  int t = threadIdx.x, l = t & 63, w = t >> 6;
  int row0 = blockIdx.x * 64 + w * 16;
  int row = row0 + (l & 15);
  bool ok = row < N;
  int rowc = ok ? row : 0;
  int koff = (l >> 4) << 3;
  const char* hp = (const char*)out;
  const bf16x8* Bp = (const bf16x8*)((const unsigned short*)(ws + FCPK_OFF) + (size_t)l * 8);
  f32x4 acc[8];
  #pragma unroll
  for (int ct = 0; ct < 8; ++ct) acc[ct] = (f32x4){0.f,0.f,0.f,0.f};

  #pragma unroll
  for (int kb = 0; kb < 8; ++kb) {
    int k0 = kb * 32 + koff;
    uint4 hr = *(const uint4*)(hp + (size_t)rowc * 512 + k0 * 2);
    const float* xb = x + (size_t)rowc * 128 + (k0 & 127);
    const float* scp = ws + SCALE_OFF + k0;
    const float* shp = ws + SHIFT_OFF + k0;
    float xs[8], sc[8], sh[8];
    ((float4*)xs)[0] = *(const float4*)xb;       ((float4*)xs)[1] = *(const float4*)(xb + 4);
    ((float4*)sc)[0] = *(const float4*)scp;      ((float4*)sc)[1] = *(const float4*)(scp + 4);
    ((float4*)sh)[0] = *(const float4*)shp;      ((float4*)sh)[1] = *(const float4*)(shp + 4);
    const unsigned* hu = (const unsigned*)&hr;
    union { bf16x8 v; unsigned u[4]; } A_;
    #pragma unroll
    for (int j = 0; j < 4; ++j) {
      float lo = bf2f(hu[j] & 0xffffu) * sc[2*j]     + sh[2*j]     + xs[2*j];
      float hi = bf2f(hu[j] >> 16)     * sc[2*j + 1] + sh[2*j + 1] + xs[2*j + 1];
      A_.u[j] = pkbf(fmaxf(lo, 0.f), fmaxf(hi, 0.f));
    }
    bf16x8 A = A_.v;
    if (!ok) A = (bf16x8){0,0,0,0,0,0,0,0};
    #pragma unroll
    for (int ct = 0; ct < 8; ++ct)
      acc[ct] = __builtin_amdgcn_mfma_f32_16x16x32_bf16(A, Bp[(kb * 8 + ct) * 64], acc[ct], 0, 0, 0);
  }

  // ---- per-wave LDS transpose (f32) -> coalesced out store ----
  char* T = smem + w * 8192;   // [16 rows][512B]
  #pragma unroll
  for (int ct = 0; ct < 8; ++ct) {
    float bias = fcb[ct * 16 + (l & 15)];
    #pragma unroll
    for (int rr = 0; rr < 4; ++rr) {
      int rowt = ((l >> 4) << 2) + rr;
      int col = ct * 16 + (l & 15);
      int ch = col >> 2;
      int cs = (ch & 24) | ((ch ^ rowt) & 7);
      *(float*)(T + rowt * 512 + cs * 16 + (col & 3) * 4) = fmaxf(acc[ct][rr] + bias, 0.f);
    }
  }
  asm volatile("s_waitcnt lgkmcnt(0)" ::: "memory");
  __builtin_amdgcn_sched_barrier(0);
  #pragma unroll
  for (int q = 0; q < 8; ++q) {
    int rowt = l >> 2, cl = ((l & 3) << 3) + q;
    int cs = (cl & 24) | ((cl ^ rowt) & 7);
    float4 v = *(const float4*)(T + rowt * 512 + cs * 16);
    int grow = row0 + rowt;
    if (grow < N) *(float4*)(out + (size_t)grow * 128 + cl * 4) = v;
  }
}

extern "C" void kernel_launch(void* const* d_in, const int* in_sizes, int n_in,
                              void* d_out, int out_size, void* d_ws, size_t ws_size,
                              hipStream_t stream) {
  const float* x    = (const float*)d_in[0];
  const float* rdf  = (const float*)d_in[1];
  const float* bdf  = (const float*)d_in[2];
  const int*   aidx = (const int*)d_in[3];
  const int*   eidx = (const int*)d_in[4];
  const float* rdfW = (const float*)d_in[5];
  const float* rdfG = (const float*)d_in[7];
  const float* rdfBe= (const float*)d_in[8];
  const float* bdfW = (const float*)d_in[9];
  const float* bdfG = (const float*)d_in[11];
  const float* bdfBe= (const float*)d_in[12];
  const float* fcW  = (const float*)d_in[13];
  const float* fcB  = (const float*)d_in[14];
  float* out = (float*)d_out;
  float* ws  = (float*)d_ws;
  int N = in_sizes[0] / 128;
  int nT = (N + 63) / 64;

  hipMemsetAsync(d_ws, 0, (size_t)ZERO_WORDS * 4, stream);
  k_prep<<<160, 512, 0, stream>>>(rdfW, bdfW, fcW, ws);
  k_seg<<<(N + 255) / 256, 256, 0, stream>>>(x, aidx, eidx, ws, N);
  k_fin<<<2048, 256, 0, stream>>>(ws);
  k_gemm<<<nT, 256, 0, stream>>>(rdf, bdf, aidx, eidx, ws, (unsigned*)d_out, N);
  k_bnfin<<<1, 256, 0, stream>>>(rdfG, rdfBe, bdfG, bdfBe, ws, N);
  k_fc<<<nT, 256, 0, stream>>>(x, fcB, ws, out, N);
}

// Round 7
// 614.502 us; speedup vs baseline: 1.4701x; 1.4701x over previous
//
#include <hip/hip_runtime.h>
#include <hip/hip_bf16.h>

#define N_GRAPHS 4096
#define N_ELE 16384
#define EPS 1e-5f

// ws layout (f32 words)
#define A_TAB_OFF 0               // 4096*64 f32 atomic sums
#define A_CNT_OFF 262144          // 4096
#define E_TAB_OFF 266240          // 16384*64
#define E_CNT_OFF 1314816         // 16384
#define STAT_OFF  1331200         // 32 copies * (256 sums + 256 sqs)
#define ZPAD_OFF  1347584         // 16B guaranteed-zero pad (OOB gload_lds target)
#define ZERO_WORDS 1347588        // memset range: everything above
#define A_TABH_OFF 1347600        // 4096*64 bf16 = 131072 words
#define E_TABH_OFF 1478672        // 16384*64 bf16 = 524288 words
#define W1PK_OFF  2002960         // 2 * 128*192 bf16 = 24576 words
#define FCPK_OFF  2027536         // 128*256 bf16 = 16384 words
#define SCALE_OFF 2043920         // 256
#define SHIFT_OFF 2044176         // 256 (contiguous after SCALE)
#define WS_WORDS  2044432         // ~8.2 MB

typedef __attribute__((ext_vector_type(8))) short bf16x8;
typedef __attribute__((ext_vector_type(4))) float f32x4;

__device__ __forceinline__ float bf2f(unsigned s) { return __uint_as_float(s << 16); }
__device__ __forceinline__ unsigned f2bf(float f) {
  unsigned u = __float_as_uint(f);
  return (u + 0x7fffu + ((u >> 16) & 1u)) >> 16;  // RNE
}
__device__ __forceinline__ unsigned pkbf(float a, float b) {
  union { __hip_bfloat16 h; unsigned short u; } ca, cb;
  ca.h = __float2bfloat16(a); cb.h = __float2bfloat16(b);
  return (unsigned)ca.u | ((unsigned)cb.u << 16);
}
__device__ __forceinline__ void gload16(const void* g, void* l) {
  __builtin_amdgcn_global_load_lds(
      (const __attribute__((address_space(1))) unsigned*)g,
      (__attribute__((address_space(3))) unsigned*)l, 16, 0, 0);
}

// ---------------- K0: pack W1,W2,fcW to bf16 in MFMA B-fragment order (same as R5) ----------------
__global__ void k_prep(const float* __restrict__ W1, const float* __restrict__ W2,
                       const float* __restrict__ fcW, float* __restrict__ ws) {
  int tid = blockIdx.x * 512 + threadIdx.x;
  if (tid < 49152) {
    unsigned short* wpk = (unsigned short*)(ws + W1PK_OFF);
    int L = tid / 24576, rem = tid % 24576;
    int ct = rem / 3072, rem2 = rem % 3072;
    int i = rem2 >> 9, lane = (rem2 >> 3) & 63, j = rem2 & 7;
    int zkb = L ? (i + 2) : (i < 2 ? i : i + 2);
    int zk = zkb * 32 + ((lane >> 4) << 3) + j;
    int kp = L ? (zk - 64) : (zk < 64 ? zk : zk - 64);
    int col = ct * 16 + (lane & 15);
    const float* W = L ? W2 : W1;
    wpk[tid] = (unsigned short)f2bf(W[col * 192 + kp]);
  } else {
    int idx = tid - 49152;  // 0..32767
    unsigned short* fpk = (unsigned short*)(ws + FCPK_OFF);
    int ct = idx >> 12, kb = (idx >> 9) & 7, lane = (idx >> 3) & 63, j = idx & 7;
    fpk[idx] = (unsigned short)f2bf(fcW[(ct * 16 + (lane & 15)) * 256 + kb * 32 + ((lane >> 4) << 3) + j]);
  }
}

// ---------------- K1: segment sums (R5 verbatim) ----------------
__global__ void k_seg(const float* __restrict__ x, const int* __restrict__ aidx,
                      const int* __restrict__ eidx, float* __restrict__ ws, int N) {
  float* A_tab = ws + A_TAB_OFF; float* A_cnt = ws + A_CNT_OFF;
  float* E_tab = ws + E_TAB_OFF; float* E_cnt = ws + E_CNT_OFF;
  int t = threadIdx.x;
  int c = t & 63, p = (t >> 6) & 1, s = t >> 7;
  int r0 = blockIdx.x * 256;
  int rend = min(r0 + 256, N);
  if (p == 0) {
    float acc = 0.f, cnt = 0.f; int cur = -1;
    for (int r = r0 + s; r < rend; r += 2) {
      int a = aidx[r];
      float v = x[(size_t)r * 128 + c];
      if (a != cur) {
        if (cur >= 0) { atomicAdd(&A_tab[cur * 64 + c], acc); if (c == 0) atomicAdd(&A_cnt[cur], cnt); }
        cur = a; acc = v; cnt = 1.f;
      } else { acc += v; cnt += 1.f; }
    }
    if (cur >= 0) { atomicAdd(&A_tab[cur * 64 + c], acc); if (c == 0) atomicAdd(&A_cnt[cur], cnt); }
  } else {
    for (int r = r0 + s; r < rend; r += 2) {
      int e = eidx[r];
      float v = x[(size_t)r * 128 + 64 + c];
      atomicAdd(&E_tab[e * 64 + c], v);
      if (c == 0) atomicAdd(&E_cnt[e], 1.f);
    }
  }
}

// ---------------- K2: mean + relu -> bf16 tables (R5 verbatim) ----------------
__global__ void k_fin(float* __restrict__ ws) {
  int i = blockIdx.x * 256 + threadIdx.x;
  unsigned* w32 = (unsigned*)ws;
  if (i < 131072) {
    int e = 2 * i;
    float cnt = fmaxf(ws[A_CNT_OFF + (e >> 6)], 1.f);
    float v0 = fmaxf(ws[A_TAB_OFF + e] / cnt, 0.f);
    float v1 = fmaxf(ws[A_TAB_OFF + e + 1] / cnt, 0.f);
    w32[A_TABH_OFF + i] = f2bf(v0) | (f2bf(v1) << 16);
  }
  if (i < 524288) {
    int e = 2 * i;
    float cnt = fmaxf(ws[E_CNT_OFF + (e >> 6)], 1.f);
    float v0 = fmaxf(ws[E_TAB_OFF + e] / cnt, 0.f);
    float v1 = fmaxf(ws[E_TAB_OFF + e + 1] / cnt, 0.f);
    w32[E_TABH_OFF + i] = f2bf(v0) | (f2bf(v1) << 16);
  }
}

// ---------------- K3: 32-row / 256-thread MFMA dual GEMM, 8 blocks/CU ----------------
// zA = smem[0:8K]  [32 rows][256B bf16: rdf k0-63 | bdf k0-63], swizzled slot=(c&8)|((c^r)&7)
// zB = smem[8K:16K][32 rows][256B bf16: pa | pe], linear dest via gload16, pre-swizzled source
// wave w: layer L=w>>1, col-quad ctp=w&1 (4 ct = 64 cols). acc[2 mt][4 cti].
__global__ __launch_bounds__(256, 8) void k_gemm(
    const float* __restrict__ rdf, const float* __restrict__ bdf,
    const int* __restrict__ aidx, const int* __restrict__ eidx,
    float* __restrict__ ws, unsigned* __restrict__ outp, int N) {
  __shared__ __align__(16) char smem[16384];
  const unsigned short* Atabh = (const unsigned short*)(ws + A_TABH_OFF);
  const unsigned short* Etabh = (const unsigned short*)(ws + E_TABH_OFF);
  const void* zpad = (const void*)(ws + ZPAD_OFF);
  int t = threadIdx.x;
  int l = t & 63, w = t >> 6;
  int row0 = blockIdx.x * 32;

  // ---- zB: pa/pe gathers via global_load_lds (4 rows = 1KB per issue, 2 per wave) ----
  #pragma unroll
  for (int ii = 0; ii < 2; ++ii) {
    int rb = (w * 2 + ii) * 4;
    int r = rb + (l >> 4);
    int srow = row0 + r;
    bool ok = srow < N;
    int s = l & 15;
    int c = (s & 8) | ((s ^ r) & 7);      // logical chunk landing at slot s (involution)
    const void* src;
    if (c < 8) { int ia = ok ? aidx[srow] : 0; src = (const void*)(Atabh + ((size_t)ia * 64 + c * 8)); }
    else       { int ie = ok ? eidx[srow] : 0; src = (const void*)(Etabh + ((size_t)ie * 64 + (c - 8) * 8)); }
    if (!ok) src = zpad;
    gload16(src, smem + 8192 + rb * 256);
  }

  // ---- zA: rdf/bdf f32 -> bf16, swizzled LDS write ----
  {
    int r = t >> 3, c0 = (t & 7) * 2;
    int row = row0 + r;
    bool ok = row < N;
    #pragma unroll
    for (int cc = 0; cc < 2; ++cc) {
      int c = c0 + cc;                     // 0..15: 0-7 rdf, 8-15 bdf
      uint4 wv;
      if (ok) {
        const float4* src = (const float4*)(c < 8 ? rdf + (size_t)row * 64 + c * 8
                                                  : bdf + (size_t)row * 64 + (c - 8) * 8);
        float4 f0 = src[0], f1 = src[1];
        wv.x = pkbf(f0.x, f0.y); wv.y = pkbf(f0.z, f0.w);
        wv.z = pkbf(f1.x, f1.y); wv.w = pkbf(f1.z, f1.w);
      } else wv = (uint4){0u, 0u, 0u, 0u};
      int slot = (c & 8) | ((c ^ r) & 7);
      *(uint4*)(smem + r * 256 + slot * 16) = wv;
    }
  }
  __syncthreads();   // drains vmcnt(0) incl. global_load_lds

  // ---- MFMA ----
  int L = w >> 1, ctp = w & 1;
  const unsigned short* WpkL = (const unsigned short*)(ws + W1PK_OFF) + L * 24576;
  f32x4 acc[2][4];
  #pragma unroll
  for (int mt = 0; mt < 2; ++mt)
    #pragma unroll
    for (int cti = 0; cti < 4; ++cti) acc[mt][cti] = (f32x4){0.f, 0.f, 0.f, 0.f};
  int half = l >> 4;
  #pragma unroll
  for (int i = 0; i < 6; ++i) {
    int inA = (i < 2);
    int kb = inA ? (L ? i + 2 : i) : (i - 2);   // zA: rdf kb0-1, bdf kb2-3; zB: pa kb0-1, pe kb2-3
    const char* base = smem + (inA ? 0 : 8192);
    int c = kb * 4 + half;
    bf16x8 af[2];
    #pragma unroll
    for (int mt = 0; mt < 2; ++mt) {
      int rr = mt * 16 + (l & 15);
      int slot = (c & 8) | ((c ^ rr) & 7);
      af[mt] = *(const bf16x8*)(base + rr * 256 + slot * 16);
    }
    #pragma unroll
    for (int cti = 0; cti < 4; ++cti) {
      int ct = ctp * 4 + cti;
      bf16x8 bfr = *(const bf16x8*)(WpkL + ((ct * 6 + i) * 64 + l) * 8);
      acc[0][cti] = __builtin_amdgcn_mfma_f32_16x16x32_bf16(af[0], bfr, acc[0][cti], 0, 0, 0);
      acc[1][cti] = __builtin_amdgcn_mfma_f32_16x16x32_bf16(af[1], bfr, acc[1][cti], 0, 0, 0);
    }
  }

  // ---- fused BN stats ----
  float* stat = ws + STAT_OFF + (blockIdx.x & 31) * 512;
  #pragma unroll
  for (int cti = 0; cti < 4; ++cti) {
    float s = 0.f, q = 0.f;
    #pragma unroll
    for (int mt = 0; mt < 2; ++mt)
      #pragma unroll
      for (int rr = 0; rr < 4; ++rr) { float v = acc[mt][cti][rr]; s += v; q += v * v; }
    s += __shfl_xor(s, 16); s += __shfl_xor(s, 32);
    q += __shfl_xor(q, 16); q += __shfl_xor(q, 32);
    if (l < 16) {
      int gc = L * 128 + (ctp * 4 + cti) * 16 + l;
      atomicAdd(&stat[gc], s);
      atomicAdd(&stat[256 + gc], q);
    }
  }
  __syncthreads();   // all waves done reading z; T aliases smem[0:16K]

  // ---- epilogue: pack bf16 pairs, swizzled transpose [32 rows][512B] ----
  #pragma unroll
  for (int cti = 0; cti < 4; ++cti)
    #pragma unroll
    for (int mt = 0; mt < 2; ++mt)
      #pragma unroll
      for (int rr = 0; rr < 4; ++rr) {
        unsigned ub = pkbf(acc[mt][cti][rr], 0.f) & 0xffffu;
        unsigned pb = (unsigned)__shfl_xor((int)ub, 1);
        if (!(l & 1)) {
          int orow = mt * 16 + ((l >> 4) << 2) + rr;
          int colp = (L * 128 + (ctp * 4 + cti) * 16 + (l & 15)) >> 1;
          int ch = colp >> 2;
          int cs = (ch & 24) | ((ch ^ orow) & 7);
          *(unsigned*)(smem + orow * 512 + cs * 16 + (colp & 3) * 4) = ub | (pb << 16);
        }
      }
  __syncthreads();
  #pragma unroll
  for (int p = 0; p < 4; ++p) {
    int e = p * 256 + t; int rr = e >> 5, v4 = e & 31;
    int cs = (v4 & 24) | ((v4 ^ rr) & 7);
    uint4 val = *(const uint4*)(smem + rr * 512 + cs * 16);
    if (row0 + rr < N) ((uint4*)outp)[(size_t)(row0 + rr) * 32 + v4] = val;
  }
}

// ---------------- K4: BN finalize -> scale/shift (R5 verbatim) ----------------
__global__ void k_bnfin(const float* __restrict__ g1, const float* __restrict__ b1,
                        const float* __restrict__ g2, const float* __restrict__ b2,
                        float* __restrict__ ws, int N) {
  int c = threadIdx.x;  // 256
  float s = 0.f, q = 0.f;
  for (int m = 0; m < 32; ++m) { s += ws[STAT_OFF + m * 512 + c]; q += ws[STAT_OFF + m * 512 + 256 + c]; }
  float inv = 1.f / (float)N;
  float mu = s * inv;
  float var = fmaxf(q * inv - mu * mu, 0.f);
  int lyr = c >> 7, cc = c & 127;
  float ga = lyr ? g2[cc] : g1[cc];
  float be = lyr ? b2[cc] : b1[cc];
  float sc = ga * rsqrtf(var + EPS);
  ws[SCALE_OFF + c] = sc;
  ws[SHIFT_OFF + c] = be - mu * sc;
}

// ---------------- K5: 32-row / 256-thread BN+res+relu + MFMA fc GEMM (in-place) ----------------
// z = smem[0:16K] [32 rows][512B bf16], slot=(c&24)|((c^r)&7). wave w: 2 ct (32 cols).
// scale/shift read from ws directly (2KB, L1-hot).
__global__ __launch_bounds__(256, 8) void k_fc(
    const float* __restrict__ x, const float* __restrict__ fcb,
    float* __restrict__ ws, float* __restrict__ out, int N) {
  __shared__ __align__(16) char smem[16384];
  int t = threadIdx.x, l = t & 63, w = t >> 6;
  int row0 = blockIdx.x * 32;
  const unsigned* hp = (const unsigned*)out;

  // ---- stage: BN + residual + relu -> bf16, swizzled LDS write (8-col quarters) ----
  {
    int r = t >> 3, g8 = t & 7;
    int row = row0 + r;
    bool ok = row < N;
    #pragma unroll
    for (int qq = 0; qq < 4; ++qq) {
      int cb = g8 * 32 + qq * 8;           // col base (0..255), 8 cols
      int c = cb >> 3;                      // chunk index 0..31
      uint4 hv = (uint4){0u, 0u, 0u, 0u};
      float4 xa = (float4){0.f,0.f,0.f,0.f}, xb = xa;
      if (ok) {
        hv = *(const uint4*)((const char*)hp + (size_t)row * 512 + c * 16);
        const float* xp = x + (size_t)row * 128 + (cb & 127);
        xa = *(const float4*)xp; xb = *(const float4*)(xp + 4);
      }
      float4 sa = *(const float4*)(ws + SCALE_OFF + cb);
      float4 sb = *(const float4*)(ws + SCALE_OFF + cb + 4);
      float4 ha = *(const float4*)(ws + SHIFT_OFF + cb);
      float4 hb = *(const float4*)(ws + SHIFT_OFF + cb + 4);
      const unsigned* hu = (const unsigned*)&hv;
      const float* xf = (const float*)&xa;   // xa,xb contiguous? not guaranteed; index explicitly
      float xv[8] = {xa.x, xa.y, xa.z, xa.w, xb.x, xb.y, xb.z, xb.w};
      float sc[8] = {sa.x, sa.y, sa.z, sa.w, sb.x, sb.y, sb.z, sb.w};
      float sh[8] = {ha.x, ha.y, ha.z, ha.w, hb.x, hb.y, hb.z, hb.w};
      (void)xf;
      uint4 wv;
      unsigned* wu = (unsigned*)&wv;
      #pragma unroll
      for (int j = 0; j < 4; ++j) {
        float lo = bf2f(hu[j] & 0xffffu) * sc[2*j]     + sh[2*j]     + xv[2*j];
        float hi = bf2f(hu[j] >> 16)     * sc[2*j + 1] + sh[2*j + 1] + xv[2*j + 1];
        wu[j] = pkbf(fmaxf(lo, 0.f), fmaxf(hi, 0.f));
      }
      int slot = (c & 24) | ((c ^ r) & 7);
      *(uint4*)(smem + r * 512 + slot * 16) = wv;
    }
  }
  __syncthreads();

  // ---- MFMA K=256: wave w -> ct = w*2 + cti ----
  f32x4 acc[2][2];
  #pragma unroll
  for (int mt = 0; mt < 2; ++mt)
    #pragma unroll
    for (int cti = 0; cti < 2; ++cti) acc[mt][cti] = (f32x4){0.f, 0.f, 0.f, 0.f};
  const unsigned short* Fpk = (const unsigned short*)(ws + FCPK_OFF);
  int half = l >> 4;
  #pragma unroll
  for (int kb = 0; kb < 8; ++kb) {
    int c = kb * 4 + half;
    bf16x8 af[2];
    #pragma unroll
    for (int mt = 0; mt < 2; ++mt) {
      int rr = mt * 16 + (l & 15);
      int slot = (c & 24) | ((c ^ rr) & 7);
      af[mt] = *(const bf16x8*)(smem + rr * 512 + slot * 16);
    }
    #pragma unroll
    for (int cti = 0; cti < 2; ++cti) {
      int ct = w * 2 + cti;
      bf16x8 bfr = *(const bf16x8*)(Fpk + ((ct * 8 + kb) * 64 + l) * 8);
      acc[0][cti] = __builtin_amdgcn_mfma_f32_16x16x32_bf16(af[0], bfr, acc[0][cti], 0, 0, 0);
      acc[1][cti] = __builtin_amdgcn_mfma_f32_16x16x32_bf16(af[1], bfr, acc[1][cti], 0, 0, 0);
    }
  }
  __syncthreads();   // done reading z; T (f32 [32][512B]) aliases smem

  // ---- epilogue: bias + relu, swizzled f32 transpose ----
  #pragma unroll
  for (int cti = 0; cti < 2; ++cti) {
    float bias = fcb[(w * 2 + cti) * 16 + (l & 15)];
    #pragma unroll
    for (int mt = 0; mt < 2; ++mt)
      #pragma unroll
      for (int rr = 0; rr < 4; ++rr) {
        int orow = mt * 16 + ((l >> 4) << 2) + rr;
        int col = (w * 2 + cti) * 16 + (l & 15);
        int ch = col >> 2;
        int cs = (ch & 24) | ((ch ^ orow) & 7);
        *(float*)(smem + orow * 512 + cs * 16 + (col & 3) * 4) = fmaxf(acc[mt][cti][rr] + bias, 0.f);
      }
  }
  __syncthreads();
  #pragma unroll
  for (int p = 0; p < 4; ++p) {
    int e = p * 256 + t; int rr = e >> 5, v4 = e & 31;
    int cs = (v4 & 24) | ((v4 ^ rr) & 7);
    float4 val = *(const float4*)(smem + rr * 512 + cs * 16);
    if (row0 + rr < N) ((float4*)out)[(size_t)(row0 + rr) * 32 + v4] = val;
  }
}

extern "C" void kernel_launch(void* const* d_in, const int* in_sizes, int n_in,
                              void* d_out, int out_size, void* d_ws, size_t ws_size,
                              hipStream_t stream) {
  const float* x    = (const float*)d_in[0];
  const float* rdf  = (const float*)d_in[1];
  const float* bdf  = (const float*)d_in[2];
  const int*   aidx = (const int*)d_in[3];
  const int*   eidx = (const int*)d_in[4];
  const float* rdfW = (const float*)d_in[5];
  const float* rdfG = (const float*)d_in[7];
  const float* rdfBe= (const float*)d_in[8];
  const float* bdfW = (const float*)d_in[9];
  const float* bdfG = (const float*)d_in[11];
  const float* bdfBe= (const float*)d_in[12];
  const float* fcW  = (const float*)d_in[13];
  const float* fcB  = (const float*)d_in[14];
  float* out = (float*)d_out;
  float* ws  = (float*)d_ws;
  int N = in_sizes[0] / 128;
  int nT32 = (N + 31) / 32;

  hipMemsetAsync(d_ws, 0, (size_t)ZERO_WORDS * 4, stream);
  k_prep<<<160, 512, 0, stream>>>(rdfW, bdfW, fcW, ws);
  k_seg<<<(N + 255) / 256, 256, 0, stream>>>(x, aidx, eidx, ws, N);
  k_fin<<<2048, 256, 0, stream>>>(ws);
  k_gemm<<<nT32, 256, 0, stream>>>(rdf, bdf, aidx, eidx, ws, (unsigned*)d_out, N);
  k_bnfin<<<1, 256, 0, stream>>>(rdfG, rdfBe, bdfG, bdfBe, ws, N);
  k_fc<<<nT32, 256, 0, stream>>>(x, fcB, ws, out, N);
}

// Round 8
// 558.736 us; speedup vs baseline: 1.6168x; 1.0998x over previous
//
#include <hip/hip_runtime.h>
#include <hip/hip_bf16.h>

#define N_GRAPHS 4096
#define N_ELE 16384
#define EPS 1e-5f
#define TPB 4   // tiles per block (pipelined)

// ws layout (f32 words)
#define A_TAB_OFF 0               // 4096*64 f32 atomic sums
#define A_CNT_OFF 262144          // 4096
#define E_TAB_OFF 266240          // 16384*64
#define E_CNT_OFF 1314816         // 16384
#define STAT_OFF  1331200         // 32 copies * (256 sums + 256 sqs)
#define ZPAD_OFF  1347584         // 16B guaranteed-zero pad (OOB gload_lds target)
#define ZERO_WORDS 1347588        // memset range: everything above
#define A_TABH_OFF 1347600        // 4096*64 bf16 = 131072 words
#define E_TABH_OFF 1478672        // 16384*64 bf16 = 524288 words
#define W1PK_OFF  2002960         // 2 * 128*192 bf16 = 24576 words
#define FCPK_OFF  2027536         // 128*256 bf16 = 16384 words
#define SCALE_OFF 2043920         // 256
#define SHIFT_OFF 2044176         // 256 (contiguous after SCALE)
#define WS_WORDS  2044432         // ~8.2 MB

typedef __attribute__((ext_vector_type(8))) short bf16x8;
typedef __attribute__((ext_vector_type(4))) float f32x4;

__device__ __forceinline__ float bf2f(unsigned s) { return __uint_as_float(s << 16); }
__device__ __forceinline__ unsigned f2bf(float f) {
  unsigned u = __float_as_uint(f);
  return (u + 0x7fffu + ((u >> 16) & 1u)) >> 16;  // RNE
}
__device__ __forceinline__ unsigned pkbf(float a, float b) {
  union { __hip_bfloat16 h; unsigned short u; } ca, cb;
  ca.h = __float2bfloat16(a); cb.h = __float2bfloat16(b);
  return (unsigned)ca.u | ((unsigned)cb.u << 16);
}
__device__ __forceinline__ void gload16(const void* g, void* l) {
  __builtin_amdgcn_global_load_lds(
      (const __attribute__((address_space(1))) unsigned*)g,
      (__attribute__((address_space(3))) unsigned*)l, 16, 0, 0);
}

// ---------------- K0: pack W1,W2,fcW to bf16 in MFMA B-fragment order (R5 fixed) ----------------
__global__ void k_prep(const float* __restrict__ W1, const float* __restrict__ W2,
                       const float* __restrict__ fcW, float* __restrict__ ws) {
  int tid = blockIdx.x * 512 + threadIdx.x;
  if (tid < 49152) {
    unsigned short* wpk = (unsigned short*)(ws + W1PK_OFF);
    int L = tid / 24576, rem = tid % 24576;
    int ct = rem / 3072, rem2 = rem % 3072;
    int i = rem2 >> 9, lane = (rem2 >> 3) & 63, j = rem2 & 7;
    int zkb = L ? (i + 2) : (i < 2 ? i : i + 2);
    int zk = zkb * 32 + ((lane >> 4) << 3) + j;
    int kp = L ? (zk - 64) : (zk < 64 ? zk : zk - 64);
    int col = ct * 16 + (lane & 15);
    const float* W = L ? W2 : W1;
    wpk[tid] = (unsigned short)f2bf(W[col * 192 + kp]);
  } else {
    int idx = tid - 49152;  // 0..32767
    unsigned short* fpk = (unsigned short*)(ws + FCPK_OFF);
    int ct = idx >> 12, kb = (idx >> 9) & 7, lane = (idx >> 3) & 63, j = idx & 7;
    fpk[idx] = (unsigned short)f2bf(fcW[(ct * 16 + (lane & 15)) * 256 + kb * 32 + ((lane >> 4) << 3) + j]);
  }
}

// ---------------- K1: segment sums (R5 verbatim) ----------------
__global__ void k_seg(const float* __restrict__ x, const int* __restrict__ aidx,
                      const int* __restrict__ eidx, float* __restrict__ ws, int N) {
  float* A_tab = ws + A_TAB_OFF; float* A_cnt = ws + A_CNT_OFF;
  float* E_tab = ws + E_TAB_OFF; float* E_cnt = ws + E_CNT_OFF;
  int t = threadIdx.x;
  int c = t & 63, p = (t >> 6) & 1, s = t >> 7;
  int r0 = blockIdx.x * 256;
  int rend = min(r0 + 256, N);
  if (p == 0) {
    float acc = 0.f, cnt = 0.f; int cur = -1;
    for (int r = r0 + s; r < rend; r += 2) {
      int a = aidx[r];
      float v = x[(size_t)r * 128 + c];
      if (a != cur) {
        if (cur >= 0) { atomicAdd(&A_tab[cur * 64 + c], acc); if (c == 0) atomicAdd(&A_cnt[cur], cnt); }
        cur = a; acc = v; cnt = 1.f;
      } else { acc += v; cnt += 1.f; }
    }
    if (cur >= 0) { atomicAdd(&A_tab[cur * 64 + c], acc); if (c == 0) atomicAdd(&A_cnt[cur], cnt); }
  } else {
    for (int r = r0 + s; r < rend; r += 2) {
      int e = eidx[r];
      float v = x[(size_t)r * 128 + 64 + c];
      atomicAdd(&E_tab[e * 64 + c], v);
      if (c == 0) atomicAdd(&E_cnt[e], 1.f);
    }
  }
}

// ---------------- K2: mean + relu -> bf16 tables (R5 verbatim) ----------------
__global__ void k_fin(float* __restrict__ ws) {
  int i = blockIdx.x * 256 + threadIdx.x;
  unsigned* w32 = (unsigned*)ws;
  if (i < 131072) {
    int e = 2 * i;
    float cnt = fmaxf(ws[A_CNT_OFF + (e >> 6)], 1.f);
    float v0 = fmaxf(ws[A_TAB_OFF + e] / cnt, 0.f);
    float v1 = fmaxf(ws[A_TAB_OFF + e + 1] / cnt, 0.f);
    w32[A_TABH_OFF + i] = f2bf(v0) | (f2bf(v1) << 16);
  }
  if (i < 524288) {
    int e = 2 * i;
    float cnt = fmaxf(ws[E_CNT_OFF + (e >> 6)], 1.f);
    float v0 = fmaxf(ws[E_TAB_OFF + e] / cnt, 0.f);
    float v1 = fmaxf(ws[E_TAB_OFF + e + 1] / cnt, 0.f);
    w32[E_TABH_OFF + i] = f2bf(v0) | (f2bf(v1) << 16);
  }
}

// ---- k_gemm staging helpers ----
__device__ __forceinline__ void stage_zb(const unsigned short* __restrict__ Atabh,
    const unsigned short* __restrict__ Etabh, const void* zpad,
    const int* __restrict__ aidx, const int* __restrict__ eidx,
    int row0, int w, int l, char* zb, int N) {
  #pragma unroll
  for (int ii = 0; ii < 2; ++ii) {
    int rb = (w * 2 + ii) * 4;
    int r = rb + (l >> 4);
    int srow = row0 + r;
    bool ok = srow < N;
    int s = l & 15;
    int c = (s & 8) | ((s ^ r) & 7);      // logical chunk landing at slot s (involution)
    const void* src;
    if (c < 8) { int ia = ok ? aidx[srow] : 0; src = (const void*)(Atabh + ((size_t)ia * 64 + c * 8)); }
    else       { int ie = ok ? eidx[srow] : 0; src = (const void*)(Etabh + ((size_t)ie * 64 + (c - 8) * 8)); }
    if (!ok) src = zpad;
    gload16(src, zb + rb * 256);
  }
}

__device__ __forceinline__ void load_za(const float* __restrict__ rdf, const float* __restrict__ bdf,
    int row0, int t, float4* fv, int N) {
  int r = t >> 3, c0 = (t & 7) * 2;
  int row = row0 + r;
  bool ok = row < N;
  #pragma unroll
  for (int cc = 0; cc < 2; ++cc) {
    int c = c0 + cc;
    if (ok) {
      const float4* src = (const float4*)(c < 8 ? rdf + (size_t)row * 64 + c * 8
                                                : bdf + (size_t)row * 64 + (c - 8) * 8);
      fv[cc * 2] = src[0]; fv[cc * 2 + 1] = src[1];
    } else {
      fv[cc * 2] = (float4){0.f, 0.f, 0.f, 0.f};
      fv[cc * 2 + 1] = (float4){0.f, 0.f, 0.f, 0.f};
    }
  }
}

__device__ __forceinline__ void cvt_za(const float4* fv, int t, char* za) {
  int r = t >> 3, c0 = (t & 7) * 2;
  #pragma unroll
  for (int cc = 0; cc < 2; ++cc) {
    int c = c0 + cc;
    uint4 wv;
    wv.x = pkbf(fv[cc * 2].x, fv[cc * 2].y);     wv.y = pkbf(fv[cc * 2].z, fv[cc * 2].w);
    wv.z = pkbf(fv[cc * 2 + 1].x, fv[cc * 2 + 1].y); wv.w = pkbf(fv[cc * 2 + 1].z, fv[cc * 2 + 1].w);
    int slot = (c & 8) | ((c ^ r) & 7);
    *(uint4*)(za + r * 256 + slot * 16) = wv;
  }
}

// ---------------- K3: pipelined 64-row MFMA dual GEMM, 4 tiles/block, dbuf LDS ----------------
__global__ __launch_bounds__(512) void k_gemm(
    const float* __restrict__ rdf, const float* __restrict__ bdf,
    const int* __restrict__ aidx, const int* __restrict__ eidx,
    float* __restrict__ ws, unsigned* __restrict__ outp, int N, int nT) {
  __shared__ __align__(16) char smem[65536];   // 2 x (zA 16K + zB 16K); T aliases current buf
  const unsigned short* Atabh = (const unsigned short*)(ws + A_TABH_OFF);
  const unsigned short* Etabh = (const unsigned short*)(ws + E_TABH_OFF);
  const void* zpad = (const void*)(ws + ZPAD_OFF);
  int t = threadIdx.x;
  int l = t & 63, w = t >> 6;
  int L = w >> 2, ctp = w & 3;
  int half = l >> 4;
  const unsigned short* WpkL = (const unsigned short*)(ws + W1PK_OFF) + L * 24576;
  float* stat = ws + STAT_OFF + (blockIdx.x & 31) * 512;
  int tile0 = blockIdx.x * TPB;
  float4 fv[4];

  // ---- prologue: stage tile0 into buf0 ----
  stage_zb(Atabh, Etabh, zpad, aidx, eidx, tile0 * 64, w, l, smem + 16384, N);
  load_za(rdf, bdf, tile0 * 64, t, fv, N);
  cvt_za(fv, t, smem);
  __syncthreads();

  for (int j = 0; j < TPB; ++j) {
    int tile = tile0 + j;
    if (tile >= nT) break;
    int cur = j & 1;
    char* bufC = smem + cur * 32768;
    char* bufN = smem + (cur ^ 1) * 32768;
    bool hasN = (j + 1 < TPB) && (tile + 1 < nT);
    if (hasN) {
      stage_zb(Atabh, Etabh, zpad, aidx, eidx, (tile + 1) * 64, w, l, bufN + 16384, N);
      load_za(rdf, bdf, (tile + 1) * 64, t, fv, N);
    }

    // ---- MFMA on bufC ----
    f32x4 acc[4][2];
    #pragma unroll
    for (int mt = 0; mt < 4; ++mt)
      #pragma unroll
      for (int cti = 0; cti < 2; ++cti) acc[mt][cti] = (f32x4){0.f, 0.f, 0.f, 0.f};
    __builtin_amdgcn_s_setprio(1);
    #pragma unroll
    for (int i = 0; i < 6; ++i) {
      int zkb = L ? (i + 2) : (i < 2 ? i : i + 2);
      int cg = zkb * 4 + half;
      const char* base = bufC + (zkb < 4 ? 0 : 16384);
      int cl = cg & 15;
      bf16x8 af[4];
      #pragma unroll
      for (int mt = 0; mt < 4; ++mt) {
        int rr = mt * 16 + (l & 15);
        int slot = (cl & 8) | ((cl ^ rr) & 7);
        af[mt] = *(const bf16x8*)(base + rr * 256 + slot * 16);
      }
      #pragma unroll
      for (int cti = 0; cti < 2; ++cti) {
        bf16x8 bfr = *(const bf16x8*)(WpkL + (((ctp * 2 + cti) * 6 + i) * 64 + l) * 8);
        #pragma unroll
        for (int mt = 0; mt < 4; ++mt)
          acc[mt][cti] = __builtin_amdgcn_mfma_f32_16x16x32_bf16(af[mt], bfr, acc[mt][cti], 0, 0, 0);
      }
    }
    __builtin_amdgcn_s_setprio(0);

    // ---- fused BN stats ----
    #pragma unroll
    for (int cti = 0; cti < 2; ++cti) {
      float s = 0.f, q = 0.f;
      #pragma unroll
      for (int mt = 0; mt < 4; ++mt)
        #pragma unroll
        for (int rr = 0; rr < 4; ++rr) { float v = acc[mt][cti][rr]; s += v; q += v * v; }
      s += __shfl_xor(s, 16); s += __shfl_xor(s, 32);
      q += __shfl_xor(q, 16); q += __shfl_xor(q, 32);
      if (l < 16) {
        int gc = L * 128 + (ctp * 2 + cti) * 16 + l;
        atomicAdd(&stat[gc], s);
        atomicAdd(&stat[256 + gc], q);
      }
    }
    __syncthreads();   // all waves done reading bufC (also drains prefetch loads)

    // ---- epilogue: pack bf16 pairs, swizzled transpose into bufC [64][512B] ----
    #pragma unroll
    for (int mt = 0; mt < 4; ++mt)
      #pragma unroll
      for (int cti = 0; cti < 2; ++cti)
        #pragma unroll
        for (int rr = 0; rr < 4; ++rr) {
          unsigned ub = pkbf(acc[mt][cti][rr], 0.f) & 0xffffu;
          unsigned pb = (unsigned)__shfl_xor((int)ub, 1);
          if (!(l & 1)) {
            int orow = mt * 16 + ((l >> 4) << 2) + rr;
            int colp = (L * 128 + (ctp * 2 + cti) * 16 + (l & 15)) >> 1;
            int ch = colp >> 2;
            int cs = ((ch ^ orow) & 7) | (ch & 24);
            *(unsigned*)(bufC + orow * 512 + cs * 16 + (colp & 3) * 4) = ub | (pb << 16);
          }
        }
    __syncthreads();
    int row0 = tile * 64;
    #pragma unroll
    for (int p = 0; p < 4; ++p) {
      int e = p * 512 + t; int rr = e >> 5, v4 = e & 31;
      int cs = ((v4 ^ rr) & 7) | (v4 & 24);
      uint4 val = *(const uint4*)(bufC + rr * 512 + cs * 16);
      if (row0 + rr < N) ((uint4*)outp)[(size_t)(row0 + rr) * 32 + v4] = val;
    }
    if (hasN) cvt_za(fv, t, bufN);
    __syncthreads();
  }
}

// ---------------- K4: BN finalize -> scale/shift (R5 verbatim) ----------------
__global__ void k_bnfin(const float* __restrict__ g1, const float* __restrict__ b1,
                        const float* __restrict__ g2, const float* __restrict__ b2,
                        float* __restrict__ ws, int N) {
  int c = threadIdx.x;  // 256
  float s = 0.f, q = 0.f;
  for (int m = 0; m < 32; ++m) { s += ws[STAT_OFF + m * 512 + c]; q += ws[STAT_OFF + m * 512 + 256 + c]; }
  float inv = 1.f / (float)N;
  float mu = s * inv;
  float var = fmaxf(q * inv - mu * mu, 0.f);
  int lyr = c >> 7, cc = c & 127;
  float ga = lyr ? g2[cc] : g1[cc];
  float be = lyr ? b2[cc] : b1[cc];
  float sc = ga * rsqrtf(var + EPS);
  ws[SCALE_OFF + c] = sc;
  ws[SHIFT_OFF + c] = be - mu * sc;
}

// ---- k_fc staging helpers: thread (r=t>>3, g=t&7) handles cols L=g*16..+15 and H=L+128.
//      x loaded ONCE (cols L) and reused for both halves (x col = z col & 127). ----
__device__ __forceinline__ void load_fc(const unsigned* __restrict__ hp, const float* __restrict__ x,
    int row0, int t, uint4* hv, float4* xv, int N) {
  int r = t >> 3, g = t & 7;
  int row = row0 + r;
  if (row < N) {
    const uint4* hs = (const uint4*)((const char*)hp + (size_t)row * 512);
    hv[0] = hs[2 * g]; hv[1] = hs[2 * g + 1]; hv[2] = hs[2 * g + 16]; hv[3] = hs[2 * g + 17];
    const float4* xs = (const float4*)(x + (size_t)row * 128 + g * 16);
    xv[0] = xs[0]; xv[1] = xs[1]; xv[2] = xs[2]; xv[3] = xs[3];
  } else {
    #pragma unroll
    for (int i = 0; i < 4; ++i) { hv[i] = (uint4){0u,0u,0u,0u}; xv[i] = (float4){0.f,0.f,0.f,0.f}; }
  }
}

__device__ __forceinline__ void proc_fc(const uint4* hv, const float4* xv, const float* scsh,
    int t, char* z) {
  int r = t >> 3, g = t & 7;
  const unsigned* hu = (const unsigned*)hv;   // [0..7]: chunks 2g,2g+1 (cols L); [8..15]: 2g+16,2g+17 (cols H)
  const float* xf = (const float*)xv;         // 16 floats, cols g*16..+15
  #pragma unroll
  for (int hh = 0; hh < 2; ++hh) {
    #pragma unroll
    for (int d = 0; d < 2; ++d) {
      uint4 wq;
      unsigned* wu = (unsigned*)&wq;
      #pragma unroll
      for (int jj = 0; jj < 4; ++jj) {
        int xi = d * 8 + 2 * jj;
        int k = g * 16 + hh * 128 + d * 8 + 2 * jj;
        unsigned hraw = hu[hh * 8 + d * 4 + jj];
        float lo = bf2f(hraw & 0xffffu) * scsh[k]     + scsh[256 + k]     + xf[xi];
        float hi = bf2f(hraw >> 16)     * scsh[k + 1] + scsh[256 + k + 1] + xf[xi + 1];
        wu[jj] = pkbf(fmaxf(lo, 0.f), fmaxf(hi, 0.f));
      }
      int c = 2 * g + hh * 16 + d;          // chunk index 0..31
      int kb = c >> 2, hf = c & 3;
      int slot = (hf << 3) | ((kb ^ r ^ hf) & 7);
      *(uint4*)(z + r * 512 + slot * 16) = wq;
    }
  }
}

// ---------------- K5: pipelined BN+res+relu + MFMA fc GEMM, 4 tiles/block, dbuf (in-place) ----------------
__global__ __launch_bounds__(512) void k_fc(
    const float* __restrict__ x, const float* __restrict__ fcb,
    float* __restrict__ ws, float* __restrict__ out, int N, int nT) {
  __shared__ __align__(16) char smem[65536];   // 2 x 32KB z-buf; T aliases current
  __shared__ float scsh[512];
  int t = threadIdx.x, l = t & 63, w = t >> 6;
  const unsigned* hp = (const unsigned*)out;
  const unsigned short* Fpk = (const unsigned short*)(ws + FCPK_OFF);
  int half = l >> 4;
  int tile0 = blockIdx.x * TPB;
  uint4 hv[4]; float4 xv[4];

  // ---- prologue ----
  scsh[t] = ws[SCALE_OFF + t];
  load_fc(hp, x, tile0 * 64, t, hv, xv, N);
  float bias = fcb[(w << 4) + (l & 15)];
  __syncthreads();                 // scsh ready
  proc_fc(hv, xv, scsh, t, smem);
  __syncthreads();

  for (int j = 0; j < TPB; ++j) {
    int tile = tile0 + j;
    if (tile >= nT) break;
    int cur = j & 1;
    char* bufC = smem + cur * 32768;
    char* bufN = smem + (cur ^ 1) * 32768;
    bool hasN = (j + 1 < TPB) && (tile + 1 < nT);
    if (hasN) load_fc(hp, x, (tile + 1) * 64, t, hv, xv, N);

    // ---- MFMA K=256: wave w -> col-tile w ----
    f32x4 acc[4];
    #pragma unroll
    for (int mt = 0; mt < 4; ++mt) acc[mt] = (f32x4){0.f, 0.f, 0.f, 0.f};
    __builtin_amdgcn_s_setprio(1);
    #pragma unroll
    for (int kb = 0; kb < 8; ++kb) {
      bf16x8 bfr = *(const bf16x8*)(Fpk + ((w * 8 + kb) * 64 + l) * 8);
      #pragma unroll
      for (int mt = 0; mt < 4; ++mt) {
        int rr = mt * 16 + (l & 15);
        int slot = ((kb ^ rr ^ half) & 7) | (half << 3);
        bf16x8 af = *(const bf16x8*)(bufC + rr * 512 + slot * 16);
        acc[mt] = __builtin_amdgcn_mfma_f32_16x16x32_bf16(af, bfr, acc[mt], 0, 0, 0);
      }
    }
    __builtin_amdgcn_s_setprio(0);
    __syncthreads();   // done reading bufC

    // ---- epilogue: bias + relu, swizzled f32 transpose into bufC ----
    #pragma unroll
    for (int mt = 0; mt < 4; ++mt)
      #pragma unroll
      for (int rr = 0; rr < 4; ++rr) {
        int orow = mt * 16 + ((l >> 4) << 2) + rr;
        int col = (w << 4) + (l & 15);
        int ch = col >> 2;
        int cs = ((ch ^ orow) & 7) | (ch & 24);
        *(float*)(bufC + orow * 512 + cs * 16 + (col & 3) * 4) = fmaxf(acc[mt][rr] + bias, 0.f);
      }
    __syncthreads();
    int row0 = tile * 64;
    #pragma unroll
    for (int p = 0; p < 4; ++p) {
      int e = p * 512 + t; int rr = e >> 5, v4 = e & 31;
      int cs = ((v4 ^ rr) & 7) | (v4 & 24);
      float4 val = *(const float4*)(bufC + rr * 512 + cs * 16);
      if (row0 + rr < N) ((float4*)out)[(size_t)(row0 + rr) * 32 + v4] = val;
    }
    if (hasN) proc_fc(hv, xv, scsh, t, bufN);
    __syncthreads();
  }
}

extern "C" void kernel_launch(void* const* d_in, const int* in_sizes, int n_in,
                              void* d_out, int out_size, void* d_ws, size_t ws_size,
                              hipStream_t stream) {
  const float* x    = (const float*)d_in[0];
  const float* rdf  = (const float*)d_in[1];
  const float* bdf  = (const float*)d_in[2];
  const int*   aidx = (const int*)d_in[3];
  const int*   eidx = (const int*)d_in[4];
  const float* rdfW = (const float*)d_in[5];
  const float* rdfG = (const float*)d_in[7];
  const float* rdfBe= (const float*)d_in[8];
  const float* bdfW = (const float*)d_in[9];
  const float* bdfG = (const float*)d_in[11];
  const float* bdfBe= (const float*)d_in[12];
  const float* fcW  = (const float*)d_in[13];
  const float* fcB  = (const float*)d_in[14];
  float* out = (float*)d_out;
  float* ws  = (float*)d_ws;
  int N = in_sizes[0] / 128;
  int nT = (N + 63) / 64;
  int gridP = (nT + TPB - 1) / TPB;

  hipMemsetAsync(d_ws, 0, (size_t)ZERO_WORDS * 4, stream);
  k_prep<<<160, 512, 0, stream>>>(rdfW, bdfW, fcW, ws);
  k_seg<<<(N + 255) / 256, 256, 0, stream>>>(x, aidx, eidx, ws, N);
  k_fin<<<2048, 256, 0, stream>>>(ws);
  k_gemm<<<gridP, 512, 0, stream>>>(rdf, bdf, aidx, eidx, ws, (unsigned*)d_out, N, nT);
  k_bnfin<<<1, 256, 0, stream>>>(rdfG, rdfBe, bdfG, bdfBe, ws, N);
  k_fc<<<gridP, 512, 0, stream>>>(x, fcB, ws, out, N, nT);
}

// Round 9
// 511.999 us; speedup vs baseline: 1.7644x; 1.0913x over previous
//
#include <hip/hip_runtime.h>
#include <hip/hip_bf16.h>

#define N_GRAPHS 4096
#define N_ELE 16384
#define EPS 1e-5f

// ws layout (f32 words)
#define A_TAB_OFF 0               // 4096*64 f32 atomic sums
#define A_CNT_OFF 262144          // 4096
#define E_TAB_OFF 266240          // 16384*64
#define E_CNT_OFF 1314816         // 16384
#define STAT_OFF  1331200         // 32 copies * (256 sums + 256 sqs)
#define ZPAD_OFF  1347584         // 16B guaranteed-zero pad (OOB gload_lds target)
#define ZERO_WORDS 1347588        // memset range: everything above
#define A_TABH_OFF 1347600        // 4096*64 bf16 = 131072 words
#define E_TABH_OFF 1478672        // 16384*64 bf16 = 524288 words
#define W1PK_OFF  2002960         // 2 * 128*192 bf16 = 24576 words
#define FCPK_OFF  2027536         // 128*256 bf16 = 16384 words
#define SCALE_OFF 2043920         // 256
#define SHIFT_OFF 2044176         // 256 (contiguous after SCALE)
#define WS_WORDS  2044432         // ~8.2 MB

typedef __attribute__((ext_vector_type(8))) short bf16x8;
typedef __attribute__((ext_vector_type(4))) float f32x4;

__device__ __forceinline__ float bf2f(unsigned s) { return __uint_as_float(s << 16); }
__device__ __forceinline__ unsigned f2bf(float f) {
  unsigned u = __float_as_uint(f);
  return (u + 0x7fffu + ((u >> 16) & 1u)) >> 16;  // RNE
}
__device__ __forceinline__ unsigned pkbf(float a, float b) {
  union { __hip_bfloat16 h; unsigned short u; } ca, cb;
  ca.h = __float2bfloat16(a); cb.h = __float2bfloat16(b);
  return (unsigned)ca.u | ((unsigned)cb.u << 16);
}
__device__ __forceinline__ void gload16(const void* g, void* l) {
  __builtin_amdgcn_global_load_lds(
      (const __attribute__((address_space(1))) unsigned*)g,
      (__attribute__((address_space(3))) unsigned*)l, 16, 0, 0);
}

// ---------------- K0: pack W1,W2,fcW to bf16 in MFMA B-fragment order (R5 verbatim) ----------------
__global__ void k_prep(const float* __restrict__ W1, const float* __restrict__ W2,
                       const float* __restrict__ fcW, float* __restrict__ ws) {
  int tid = blockIdx.x * 512 + threadIdx.x;
  if (tid < 49152) {
    unsigned short* wpk = (unsigned short*)(ws + W1PK_OFF);
    int L = tid / 24576, rem = tid % 24576;
    int ct = rem / 3072, rem2 = rem % 3072;
    int i = rem2 >> 9, lane = (rem2 >> 3) & 63, j = rem2 & 7;
    int zkb = L ? (i + 2) : (i < 2 ? i : i + 2);
    int zk = zkb * 32 + ((lane >> 4) << 3) + j;
    int kp = L ? (zk - 64) : (zk < 64 ? zk : zk - 64);
    int col = ct * 16 + (lane & 15);
    const float* W = L ? W2 : W1;
    wpk[tid] = (unsigned short)f2bf(W[col * 192 + kp]);
  } else {
    int idx = tid - 49152;  // 0..32767
    unsigned short* fpk = (unsigned short*)(ws + FCPK_OFF);
    int ct = idx >> 12, kb = (idx >> 9) & 7, lane = (idx >> 3) & 63, j = idx & 7;
    fpk[idx] = (unsigned short)f2bf(fcW[(ct * 16 + (lane & 15)) * 256 + kb * 32 + ((lane >> 4) << 3) + j]);
  }
}

// ---------------- K1: segment sums (R5 verbatim) ----------------
__global__ void k_seg(const float* __restrict__ x, const int* __restrict__ aidx,
                      const int* __restrict__ eidx, float* __restrict__ ws, int N) {
  float* A_tab = ws + A_TAB_OFF; float* A_cnt = ws + A_CNT_OFF;
  float* E_tab = ws + E_TAB_OFF; float* E_cnt = ws + E_CNT_OFF;
  int t = threadIdx.x;
  int c = t & 63, p = (t >> 6) & 1, s = t >> 7;
  int r0 = blockIdx.x * 256;
  int rend = min(r0 + 256, N);
  if (p == 0) {
    float acc = 0.f, cnt = 0.f; int cur = -1;
    for (int r = r0 + s; r < rend; r += 2) {
      int a = aidx[r];
      float v = x[(size_t)r * 128 + c];
      if (a != cur) {
        if (cur >= 0) { atomicAdd(&A_tab[cur * 64 + c], acc); if (c == 0) atomicAdd(&A_cnt[cur], cnt); }
        cur = a; acc = v; cnt = 1.f;
      } else { acc += v; cnt += 1.f; }
    }
    if (cur >= 0) { atomicAdd(&A_tab[cur * 64 + c], acc); if (c == 0) atomicAdd(&A_cnt[cur], cnt); }
  } else {
    for (int r = r0 + s; r < rend; r += 2) {
      int e = eidx[r];
      float v = x[(size_t)r * 128 + 64 + c];
      atomicAdd(&E_tab[e * 64 + c], v);
      if (c == 0) atomicAdd(&E_cnt[e], 1.f);
    }
  }
}

// ---------------- K2: mean + relu -> bf16 tables (R5 verbatim) ----------------
__global__ void k_fin(float* __restrict__ ws) {
  int i = blockIdx.x * 256 + threadIdx.x;
  unsigned* w32 = (unsigned*)ws;
  if (i < 131072) {
    int e = 2 * i;
    float cnt = fmaxf(ws[A_CNT_OFF + (e >> 6)], 1.f);
    float v0 = fmaxf(ws[A_TAB_OFF + e] / cnt, 0.f);
    float v1 = fmaxf(ws[A_TAB_OFF + e + 1] / cnt, 0.f);
    w32[A_TABH_OFF + i] = f2bf(v0) | (f2bf(v1) << 16);
  }
  if (i < 524288) {
    int e = 2 * i;
    float cnt = fmaxf(ws[E_CNT_OFF + (e >> 6)], 1.f);
    float v0 = fmaxf(ws[E_TAB_OFF + e] / cnt, 0.f);
    float v1 = fmaxf(ws[E_TAB_OFF + e + 1] / cnt, 0.f);
    w32[E_TABH_OFF + i] = f2bf(v0) | (f2bf(v1) << 16);
  }
}

// ---------------- K3: 64-row MFMA dual GEMM, 4 waves (256 thr), R5 algebra ----------------
// zA = smem[0:16K]  [64 rows][256B bf16: rdf | bdf], slot=(c&8)|((c^r)&7)
// zB = smem[16K:32K][64 rows][256B bf16: pa | pe], gload16 linear dest, pre-swizzled src
// wave w: L = w>>1, ct = (w&1)*4 + cti (cti 0..3). 96 MFMA/wave.
__global__ __launch_bounds__(256) void k_gemm(
    const float* __restrict__ rdf, const float* __restrict__ bdf,
    const int* __restrict__ aidx, const int* __restrict__ eidx,
    float* __restrict__ ws, unsigned* __restrict__ outp, int N) {
  __shared__ __align__(16) char smem[32768];
  const unsigned short* Atabh = (const unsigned short*)(ws + A_TABH_OFF);
  const unsigned short* Etabh = (const unsigned short*)(ws + E_TABH_OFF);
  const void* zpad = (const void*)(ws + ZPAD_OFF);
  int t = threadIdx.x;
  int l = t & 63, w = t >> 6;
  int row0 = blockIdx.x * 64;

  // ---- hoist idx loads for all 4 gather issues, then issue gathers ----
  int ia4[4], ie4[4];
  #pragma unroll
  for (int ii = 0; ii < 4; ++ii) {
    int srow = row0 + (w * 4 + ii) * 4 + (l >> 4);
    bool okr = srow < N;
    int rc = okr ? srow : 0;
    ia4[ii] = okr ? aidx[rc] : -1;
    ie4[ii] = okr ? eidx[rc] : -1;
  }
  #pragma unroll
  for (int ii = 0; ii < 4; ++ii) {
    int rb = (w * 4 + ii) * 4;
    int r = rb + (l >> 4);
    int s = l & 15;
    int c = (s & 8) | ((s ^ r) & 7);      // chunk landing at slot s (involution)
    const void* src;
    if (c < 8) src = (ia4[ii] >= 0) ? (const void*)(Atabh + ((size_t)ia4[ii] * 64 + c * 8)) : zpad;
    else       src = (ie4[ii] >= 0) ? (const void*)(Etabh + ((size_t)ie4[ii] * 64 + (c - 8) * 8)) : zpad;
    gload16(src, smem + 16384 + rb * 256);
  }

  // ---- zA: rdf/bdf f32 -> bf16, swizzled LDS write (4 chunks/thread) ----
  {
    int r = t >> 2, c0 = (t & 3) * 4;
    int row = row0 + r;
    bool ok = row < N;
    #pragma unroll
    for (int cc = 0; cc < 4; ++cc) {
      int c = c0 + cc;
      uint4 wv;
      if (ok) {
        const float4* src = (const float4*)(c < 8 ? rdf + (size_t)row * 64 + c * 8
                                                  : bdf + (size_t)row * 64 + (c - 8) * 8);
        float4 f0 = src[0], f1 = src[1];
        wv.x = pkbf(f0.x, f0.y); wv.y = pkbf(f0.z, f0.w);
        wv.z = pkbf(f1.x, f1.y); wv.w = pkbf(f1.z, f1.w);
      } else wv = (uint4){0u, 0u, 0u, 0u};
      int slot = (c & 8) | ((c ^ r) & 7);
      *(uint4*)(smem + r * 256 + slot * 16) = wv;
    }
  }
  __syncthreads();   // drains vmcnt(0) incl. global_load_lds

  // ---- MFMA: wave w -> L = w>>1, ct = (w&1)*4 + cti ----
  int L = w >> 1, cq = w & 1;
  const unsigned short* WpkL = (const unsigned short*)(ws + W1PK_OFF) + L * 24576;
  f32x4 acc[4][4];
  #pragma unroll
  for (int mt = 0; mt < 4; ++mt)
    #pragma unroll
    for (int cti = 0; cti < 4; ++cti) acc[mt][cti] = (f32x4){0.f, 0.f, 0.f, 0.f};
  int half = l >> 4;
  __builtin_amdgcn_s_setprio(1);
  #pragma unroll
  for (int i = 0; i < 6; ++i) {
    int zkb = L ? (i + 2) : (i < 2 ? i : i + 2);
    int cg = zkb * 4 + half;
    const char* base = smem + (zkb < 4 ? 0 : 16384);
    int cl = cg & 15;
    bf16x8 af[4];
    #pragma unroll
    for (int mt = 0; mt < 4; ++mt) {
      int rr = mt * 16 + (l & 15);
      int slot = (cl & 8) | ((cl ^ rr) & 7);
      af[mt] = *(const bf16x8*)(base + rr * 256 + slot * 16);
    }
    #pragma unroll
    for (int cti = 0; cti < 4; ++cti) {
      int ct = cq * 4 + cti;
      bf16x8 bfr = *(const bf16x8*)(WpkL + ((ct * 6 + i) * 64 + l) * 8);
      #pragma unroll
      for (int mt = 0; mt < 4; ++mt)
        acc[mt][cti] = __builtin_amdgcn_mfma_f32_16x16x32_bf16(af[mt], bfr, acc[mt][cti], 0, 0, 0);
    }
  }
  __builtin_amdgcn_s_setprio(0);

  // ---- fused BN stats ----
  float* stat = ws + STAT_OFF + (blockIdx.x & 31) * 512;
  #pragma unroll
  for (int cti = 0; cti < 4; ++cti) {
    float s = 0.f, q = 0.f;
    #pragma unroll
    for (int mt = 0; mt < 4; ++mt)
      #pragma unroll
      for (int rr = 0; rr < 4; ++rr) { float v = acc[mt][cti][rr]; s += v; q += v * v; }
    s += __shfl_xor(s, 16); s += __shfl_xor(s, 32);
    q += __shfl_xor(q, 16); q += __shfl_xor(q, 32);
    if (l < 16) {
      int gc = L * 128 + (cq * 4 + cti) * 16 + l;
      atomicAdd(&stat[gc], s);
      atomicAdd(&stat[256 + gc], q);
    }
  }
  __syncthreads();   // all waves done reading z; T [64][512B] aliases smem

  // ---- epilogue: pack bf16 pairs, swizzled transpose ----
  #pragma unroll
  for (int mt = 0; mt < 4; ++mt)
    #pragma unroll
    for (int cti = 0; cti < 4; ++cti)
      #pragma unroll
      for (int rr = 0; rr < 4; ++rr) {
        unsigned ub = pkbf(acc[mt][cti][rr], 0.f) & 0xffffu;
        unsigned pb = (unsigned)__shfl_xor((int)ub, 1);
        if (!(l & 1)) {
          int orow = mt * 16 + ((l >> 4) << 2) + rr;
          int colp = (L * 128 + (cq * 4 + cti) * 16 + (l & 15)) >> 1;
          int ch = colp >> 2;
          int cs = ((ch ^ orow) & 7) | (ch & 24);
          *(unsigned*)(smem + orow * 512 + cs * 16 + (colp & 3) * 4) = ub | (pb << 16);
        }
      }
  __syncthreads();
  #pragma unroll
  for (int p = 0; p < 8; ++p) {
    int e = p * 256 + t; int rr = e >> 5, v4 = e & 31;
    int cs = ((v4 ^ rr) & 7) | (v4 & 24);
    uint4 val = *(const uint4*)(smem + rr * 512 + cs * 16);
    if (row0 + rr < N) ((uint4*)outp)[(size_t)(row0 + rr) * 32 + v4] = val;
  }
}

// ---------------- K4: BN finalize -> scale/shift (R5 verbatim) ----------------
__global__ void k_bnfin(const float* __restrict__ g1, const float* __restrict__ b1,
                        const float* __restrict__ g2, const float* __restrict__ b2,
                        float* __restrict__ ws, int N) {
  int c = threadIdx.x;  // 256
  float s = 0.f, q = 0.f;
  for (int m = 0; m < 32; ++m) { s += ws[STAT_OFF + m * 512 + c]; q += ws[STAT_OFF + m * 512 + 256 + c]; }
  float inv = 1.f / (float)N;
  float mu = s * inv;
  float var = fmaxf(q * inv - mu * mu, 0.f);
  int lyr = c >> 7, cc = c & 127;
  float ga = lyr ? g2[cc] : g1[cc];
  float be = lyr ? b2[cc] : b1[cc];
  float sc = ga * rsqrtf(var + EPS);
  ws[SCALE_OFF + c] = sc;
  ws[SHIFT_OFF + c] = be - mu * sc;
}

// ---- k_fc staging (R8-verified formulas, explicit row param) ----
__device__ __forceinline__ void load_fc(const unsigned* __restrict__ hp, const float* __restrict__ x,
    int row, int g, uint4* hv, float4* xv, int N) {
  if (row < N) {
    const uint4* hs = (const uint4*)((const char*)hp + (size_t)row * 512);
    hv[0] = hs[2 * g]; hv[1] = hs[2 * g + 1]; hv[2] = hs[2 * g + 16]; hv[3] = hs[2 * g + 17];
    const float4* xs = (const float4*)(x + (size_t)row * 128 + g * 16);
    xv[0] = xs[0]; xv[1] = xs[1]; xv[2] = xs[2]; xv[3] = xs[3];
  } else {
    #pragma unroll
    for (int i = 0; i < 4; ++i) { hv[i] = (uint4){0u,0u,0u,0u}; xv[i] = (float4){0.f,0.f,0.f,0.f}; }
  }
}

__device__ __forceinline__ void proc_fc(const uint4* hv, const float4* xv, const float* scsh,
    int r, int g, char* z) {
  const unsigned* hu = (const unsigned*)hv;
  const float* xf = (const float*)xv;
  #pragma unroll
  for (int hh = 0; hh < 2; ++hh) {
    #pragma unroll
    for (int d = 0; d < 2; ++d) {
      uint4 wq;
      unsigned* wu = (unsigned*)&wq;
      #pragma unroll
      for (int jj = 0; jj < 4; ++jj) {
        int xi = d * 8 + 2 * jj;
        int k = g * 16 + hh * 128 + d * 8 + 2 * jj;
        unsigned hraw = hu[hh * 8 + d * 4 + jj];
        float lo = bf2f(hraw & 0xffffu) * scsh[k]     + scsh[256 + k]     + xf[xi];
        float hi = bf2f(hraw >> 16)     * scsh[k + 1] + scsh[256 + k + 1] + xf[xi + 1];
        wu[jj] = pkbf(fmaxf(lo, 0.f), fmaxf(hi, 0.f));
      }
      int c = 2 * g + hh * 16 + d;          // chunk index 0..31
      int kb = c >> 2, hf = c & 3;
      int slot = (hf << 3) | ((kb ^ r ^ hf) & 7);
      *(uint4*)(z + r * 512 + slot * 16) = wq;
    }
  }
}

// ---------------- K5: 64-row BN+res+relu + MFMA fc GEMM, 4 waves (in-place) ----------------
__global__ __launch_bounds__(256) void k_fc(
    const float* __restrict__ x, const float* __restrict__ fcb,
    float* __restrict__ ws, float* __restrict__ out, int N) {
  __shared__ __align__(16) char smem[32768];
  __shared__ float scsh[512];
  int t = threadIdx.x, l = t & 63, w = t >> 6;
  int row0 = blockIdx.x * 64;
  const unsigned* hp = (const unsigned*)out;
  scsh[t] = ws[SCALE_OFF + t];
  scsh[t + 256] = ws[SCALE_OFF + t + 256];

  // ---- stage 64 rows in 2 passes (loads batched ahead of both procs) ----
  int rg = t >> 3, g = t & 7;
  uint4 hv[2][4]; float4 xv[2][4];
  load_fc(hp, x, row0 + rg, g, hv[0], xv[0], N);
  load_fc(hp, x, row0 + 32 + rg, g, hv[1], xv[1], N);
  __syncthreads();   // scsh ready
  proc_fc(hv[0], xv[0], scsh, rg, g, smem);
  proc_fc(hv[1], xv[1], scsh, 32 + rg, g, smem);
  __syncthreads();

  // ---- MFMA K=256: wave w -> ct = w*2 + cti ----
  f32x4 acc[4][2];
  #pragma unroll
  for (int mt = 0; mt < 4; ++mt)
    #pragma unroll
    for (int cti = 0; cti < 2; ++cti) acc[mt][cti] = (f32x4){0.f, 0.f, 0.f, 0.f};
  const unsigned short* Fpk = (const unsigned short*)(ws + FCPK_OFF);
  int half = l >> 4;
  __builtin_amdgcn_s_setprio(1);
  #pragma unroll
  for (int kb = 0; kb < 8; ++kb) {
    bf16x8 af[4];
    #pragma unroll
    for (int mt = 0; mt < 4; ++mt) {
      int rr = mt * 16 + (l & 15);
      int slot = ((kb ^ rr ^ half) & 7) | (half << 3);
      af[mt] = *(const bf16x8*)(smem + rr * 512 + slot * 16);
    }
    #pragma unroll
    for (int cti = 0; cti < 2; ++cti) {
      int ct = w * 2 + cti;
      bf16x8 bfr = *(const bf16x8*)(Fpk + ((ct * 8 + kb) * 64 + l) * 8);
      #pragma unroll
      for (int mt = 0; mt < 4; ++mt)
        acc[mt][cti] = __builtin_amdgcn_mfma_f32_16x16x32_bf16(af[mt], bfr, acc[mt][cti], 0, 0, 0);
    }
  }
  __builtin_amdgcn_s_setprio(0);
  __syncthreads();   // done reading z; T (f32 [64][512B]) aliases smem

  // ---- epilogue: bias + relu, swizzled f32 transpose ----
  #pragma unroll
  for (int cti = 0; cti < 2; ++cti) {
    float bias = fcb[(w * 2 + cti) * 16 + (l & 15)];
    #pragma unroll
    for (int mt = 0; mt < 4; ++mt)
      #pragma unroll
      for (int rr = 0; rr < 4; ++rr) {
        int orow = mt * 16 + ((l >> 4) << 2) + rr;
        int col = (w * 2 + cti) * 16 + (l & 15);
        int ch = col >> 2;
        int cs = ((ch ^ orow) & 7) | (ch & 24);
        *(float*)(smem + orow * 512 + cs * 16 + (col & 3) * 4) = fmaxf(acc[mt][cti][rr] + bias, 0.f);
      }
  }
  __syncthreads();
  #pragma unroll
  for (int p = 0; p < 8; ++p) {
    int e = p * 256 + t; int rr = e >> 5, v4 = e & 31;
    int cs = ((v4 ^ rr) & 7) | (v4 & 24);
    float4 val = *(const float4*)(smem + rr * 512 + cs * 16);
    if (row0 + rr < N) ((float4*)out)[(size_t)(row0 + rr) * 32 + v4] = val;
  }
}

extern "C" void kernel_launch(void* const* d_in, const int* in_sizes, int n_in,
                              void* d_out, int out_size, void* d_ws, size_t ws_size,
                              hipStream_t stream) {
  const float* x    = (const float*)d_in[0];
  const float* rdf  = (const float*)d_in[1];
  const float* bdf  = (const float*)d_in[2];
  const int*   aidx = (const int*)d_in[3];
  const int*   eidx = (const int*)d_in[4];
  const float* rdfW = (const float*)d_in[5];
  const float* rdfG = (const float*)d_in[7];
  const float* rdfBe= (const float*)d_in[8];
  const float* bdfW = (const float*)d_in[9];
  const float* bdfG = (const float*)d_in[11];
  const float* bdfBe= (const float*)d_in[12];
  const float* fcW  = (const float*)d_in[13];
  const float* fcB  = (const float*)d_in[14];
  float* out = (float*)d_out;
  float* ws  = (float*)d_ws;
  int N = in_sizes[0] / 128;
  int nT = (N + 63) / 64;

  hipMemsetAsync(d_ws, 0, (size_t)ZERO_WORDS * 4, stream);
  k_prep<<<160, 512, 0, stream>>>(rdfW, bdfW, fcW, ws);
  k_seg<<<(N + 255) / 256, 256, 0, stream>>>(x, aidx, eidx, ws, N);
  k_fin<<<2048, 256, 0, stream>>>(ws);
  k_gemm<<<nT, 256, 0, stream>>>(rdf, bdf, aidx, eidx, ws, (unsigned*)d_out, N);
  k_bnfin<<<1, 256, 0, stream>>>(rdfG, rdfBe, bdfG, bdfBe, ws, N);
  k_fc<<<nT, 256, 0, stream>>>(x, fcB, ws, out, N);
}

// Round 10
// 454.993 us; speedup vs baseline: 1.9854x; 1.1253x over previous
//
#include <hip/hip_runtime.h>
#include <hip/hip_bf16.h>

#define N_GRAPHS 4096
#define N_ELE 16384
#define EPS 1e-5f

// ws layout (f32 words)
#define A_TAB_OFF 0               // 4096*64 f32 atomic sums
#define A_CNT_OFF 262144          // 4096
#define E_TAB_OFF 266240          // 16384*64
#define E_CNT_OFF 1314816         // 16384
#define STAT_OFF  1331200         // 32 copies * (256 sums + 256 sqs)
#define ZPAD_OFF  1347584         // 16B guaranteed-zero pad (OOB gload_lds target)
#define ZERO_WORDS 1347588        // memset range: everything above
#define A_TABH_OFF 1347600        // 4096*64 bf16 = 131072 words
#define E_TABH_OFF 1478672        // 16384*64 bf16 = 524288 words
#define W1PK_OFF  2002960         // 2 * 128*192 bf16 = 24576 words
#define FCPK_OFF  2027536         // 128*256 bf16 = 16384 words
#define SCALE_OFF 2043920         // 256
#define SHIFT_OFF 2044176         // 256 (contiguous after SCALE)
#define WS_WORDS  2044432         // ~8.2 MB

typedef __attribute__((ext_vector_type(8))) short bf16x8;
typedef __attribute__((ext_vector_type(4))) float f32x4;

__device__ __forceinline__ float bf2f(unsigned s) { return __uint_as_float(s << 16); }
__device__ __forceinline__ unsigned f2bf(float f) {
  unsigned u = __float_as_uint(f);
  return (u + 0x7fffu + ((u >> 16) & 1u)) >> 16;  // RNE
}
__device__ __forceinline__ unsigned pkbf(float a, float b) {
  union { __hip_bfloat16 h; unsigned short u; } ca, cb;
  ca.h = __float2bfloat16(a); cb.h = __float2bfloat16(b);
  return (unsigned)ca.u | ((unsigned)cb.u << 16);
}
__device__ __forceinline__ void gload16(const void* g, void* l) {
  __builtin_amdgcn_global_load_lds(
      (const __attribute__((address_space(1))) unsigned*)g,
      (__attribute__((address_space(3))) unsigned*)l, 16, 0, 0);
}
// bijective XCD-chunk swizzle (m204): blocks on one XCD get contiguous tiles
__device__ __forceinline__ int xcd_tile(int bid, int nT) {
  if (nT < 8) return bid;
  int q = nT >> 3, r8 = nT & 7;
  int xcd = bid & 7, i = bid >> 3;
  return (xcd < r8 ? xcd * (q + 1) : r8 * (q + 1) + (xcd - r8) * q) + i;
}

// ---------------- K0: pack W1,W2,fcW to bf16 in MFMA B-fragment order (R5 verbatim) ----------------
__global__ void k_prep(const float* __restrict__ W1, const float* __restrict__ W2,
                       const float* __restrict__ fcW, float* __restrict__ ws) {
  int tid = blockIdx.x * 512 + threadIdx.x;
  if (tid < 49152) {
    unsigned short* wpk = (unsigned short*)(ws + W1PK_OFF);
    int L = tid / 24576, rem = tid % 24576;
    int ct = rem / 3072, rem2 = rem % 3072;
    int i = rem2 >> 9, lane = (rem2 >> 3) & 63, j = rem2 & 7;
    int zkb = L ? (i + 2) : (i < 2 ? i : i + 2);
    int zk = zkb * 32 + ((lane >> 4) << 3) + j;
    int kp = L ? (zk - 64) : (zk < 64 ? zk : zk - 64);
    int col = ct * 16 + (lane & 15);
    const float* W = L ? W2 : W1;
    wpk[tid] = (unsigned short)f2bf(W[col * 192 + kp]);
  } else {
    int idx = tid - 49152;  // 0..32767
    unsigned short* fpk = (unsigned short*)(ws + FCPK_OFF);
    int ct = idx >> 12, kb = (idx >> 9) & 7, lane = (idx >> 3) & 63, j = idx & 7;
    fpk[idx] = (unsigned short)f2bf(fcW[(ct * 16 + (lane & 15)) * 256 + kb * 32 + ((lane >> 4) << 3) + j]);
  }
}

// ---------------- K1: segment sums (R5 verbatim) ----------------
__global__ void k_seg(const float* __restrict__ x, const int* __restrict__ aidx,
                      const int* __restrict__ eidx, float* __restrict__ ws, int N) {
  float* A_tab = ws + A_TAB_OFF; float* A_cnt = ws + A_CNT_OFF;
  float* E_tab = ws + E_TAB_OFF; float* E_cnt = ws + E_CNT_OFF;
  int t = threadIdx.x;
  int c = t & 63, p = (t >> 6) & 1, s = t >> 7;
  int r0 = blockIdx.x * 256;
  int rend = min(r0 + 256, N);
  if (p == 0) {
    float acc = 0.f, cnt = 0.f; int cur = -1;
    for (int r = r0 + s; r < rend; r += 2) {
      int a = aidx[r];
      float v = x[(size_t)r * 128 + c];
      if (a != cur) {
        if (cur >= 0) { atomicAdd(&A_tab[cur * 64 + c], acc); if (c == 0) atomicAdd(&A_cnt[cur], cnt); }
        cur = a; acc = v; cnt = 1.f;
      } else { acc += v; cnt += 1.f; }
    }
    if (cur >= 0) { atomicAdd(&A_tab[cur * 64 + c], acc); if (c == 0) atomicAdd(&A_cnt[cur], cnt); }
  } else {
    for (int r = r0 + s; r < rend; r += 2) {
      int e = eidx[r];
      float v = x[(size_t)r * 128 + 64 + c];
      atomicAdd(&E_tab[e * 64 + c], v);
      if (c == 0) atomicAdd(&E_cnt[e], 1.f);
    }
  }
}

// ---------------- K2: mean + relu -> bf16 tables (R5 verbatim) ----------------
__global__ void k_fin(float* __restrict__ ws) {
  int i = blockIdx.x * 256 + threadIdx.x;
  unsigned* w32 = (unsigned*)ws;
  if (i < 131072) {
    int e = 2 * i;
    float cnt = fmaxf(ws[A_CNT_OFF + (e >> 6)], 1.f);
    float v0 = fmaxf(ws[A_TAB_OFF + e] / cnt, 0.f);
    float v1 = fmaxf(ws[A_TAB_OFF + e + 1] / cnt, 0.f);
    w32[A_TABH_OFF + i] = f2bf(v0) | (f2bf(v1) << 16);
  }
  if (i < 524288) {
    int e = 2 * i;
    float cnt = fmaxf(ws[E_CNT_OFF + (e >> 6)], 1.f);
    float v0 = fmaxf(ws[E_TAB_OFF + e] / cnt, 0.f);
    float v1 = fmaxf(ws[E_TAB_OFF + e + 1] / cnt, 0.f);
    w32[E_TABH_OFF + i] = f2bf(v0) | (f2bf(v1) << 16);
  }
}

// ---------------- K3: MFMA dual GEMM (R5 structure) + B-in-regs + XCD swizzle ----------------
__global__ __launch_bounds__(512) void k_gemm(
    const float* __restrict__ rdf, const float* __restrict__ bdf,
    const int* __restrict__ aidx, const int* __restrict__ eidx,
    float* __restrict__ ws, unsigned* __restrict__ outp, int N, int nT) {
  __shared__ __align__(16) char smem[32768];
  const unsigned short* Atabh = (const unsigned short*)(ws + A_TABH_OFF);
  const unsigned short* Etabh = (const unsigned short*)(ws + E_TABH_OFF);
  const void* zpad = (const void*)(ws + ZPAD_OFF);
  int t = threadIdx.x;
  int l = t & 63, w = t >> 6;
  int tile = xcd_tile(blockIdx.x, nT);
  int row0 = tile * 64;
  int L = w >> 2, ctp = w & 3;
  const unsigned short* WpkL = (const unsigned short*)(ws + W1PK_OFF) + L * 24576;

  // ---- B-frag preload: 12 independent L2-hot loads, drained by the staging barrier ----
  bf16x8 Bfr[12];
  #pragma unroll
  for (int i = 0; i < 6; ++i)
    #pragma unroll
    for (int cti = 0; cti < 2; ++cti)
      Bfr[i * 2 + cti] = *(const bf16x8*)(WpkL + (((ctp * 2 + cti) * 6 + i) * 64 + l) * 8);

  // ---- zB: pa/pe gathers via global_load_lds, pre-swizzled per-lane source ----
  #pragma unroll
  for (int ii = 0; ii < 2; ++ii) {
    int rb = (w * 2 + ii) * 4;            // 4 rows per wave-issue
    int r = rb + (l >> 4);
    int srow = row0 + r;
    bool ok = srow < N;
    int s = l & 15;
    int c = (s & 8) | ((s ^ r) & 7);      // logical chunk landing at slot s (involution)
    const void* src;
    if (c < 8) { int ia = ok ? aidx[srow] : 0; src = (const void*)(Atabh + ((size_t)ia * 64 + c * 8)); }
    else       { int ie = ok ? eidx[srow] : 0; src = (const void*)(Etabh + ((size_t)ie * 64 + (c - 8) * 8)); }
    if (!ok) src = zpad;
    gload16(src, smem + 16384 + rb * 256);
  }

  // ---- zA: rdf/bdf f32 -> bf16, short-lived reg staging, swizzled LDS write ----
  {
    int r = t >> 3, c0 = (t & 7) * 2;
    int row = row0 + r;
    bool ok = row < N;
    #pragma unroll
    for (int cc = 0; cc < 2; ++cc) {
      int c = c0 + cc;
      uint4 wv;
      if (ok) {
        const float4* src = (const float4*)(c < 8 ? rdf + (size_t)row * 64 + c * 8
                                                  : bdf + (size_t)row * 64 + (c - 8) * 8);
        float4 f0 = src[0], f1 = src[1];
        wv.x = pkbf(f0.x, f0.y); wv.y = pkbf(f0.z, f0.w);
        wv.z = pkbf(f1.x, f1.y); wv.w = pkbf(f1.z, f1.w);
      } else wv = (uint4){0u, 0u, 0u, 0u};
      int slot = (c & 8) | ((c ^ r) & 7);
      *(uint4*)(smem + r * 256 + slot * 16) = wv;
    }
  }
  __syncthreads();   // drains vmcnt(0): gathers, zA, and the 12 B-frags

  // ---- MFMA: pure LDS + registers, no global ops ----
  f32x4 acc[4][2];
  #pragma unroll
  for (int mt = 0; mt < 4; ++mt)
    #pragma unroll
    for (int cti = 0; cti < 2; ++cti) acc[mt][cti] = (f32x4){0.f, 0.f, 0.f, 0.f};
  int half = l >> 4;
  #pragma unroll
  for (int i = 0; i < 6; ++i) {
    int zkb = L ? (i + 2) : (i < 2 ? i : i + 2);
    int cg = zkb * 4 + half;
    const char* base = smem + (zkb < 4 ? 0 : 16384);
    int cl = cg & 15;
    bf16x8 af[4];
    #pragma unroll
    for (int mt = 0; mt < 4; ++mt) {
      int rr = mt * 16 + (l & 15);
      int slot = (cl & 8) | ((cl ^ rr) & 7);
      af[mt] = *(const bf16x8*)(base + rr * 256 + slot * 16);
    }
    #pragma unroll
    for (int cti = 0; cti < 2; ++cti) {
      #pragma unroll
      for (int mt = 0; mt < 4; ++mt)
        acc[mt][cti] = __builtin_amdgcn_mfma_f32_16x16x32_bf16(af[mt], Bfr[i * 2 + cti], acc[mt][cti], 0, 0, 0);
    }
  }

  // ---- fused BN stats: reduce -> 32-copy atomics ----
  float* stat = ws + STAT_OFF + (blockIdx.x & 31) * 512;
  #pragma unroll
  for (int cti = 0; cti < 2; ++cti) {
    float s = 0.f, q = 0.f;
    #pragma unroll
    for (int mt = 0; mt < 4; ++mt)
      #pragma unroll
      for (int rr = 0; rr < 4; ++rr) { float v = acc[mt][cti][rr]; s += v; q += v * v; }
    s += __shfl_xor(s, 16); s += __shfl_xor(s, 32);
    q += __shfl_xor(q, 16); q += __shfl_xor(q, 32);
    if (l < 16) {
      int gc = L * 128 + (ctp * 2 + cti) * 16 + l;
      atomicAdd(&stat[gc], s);
      atomicAdd(&stat[256 + gc], q);
    }
  }
  __syncthreads();   // all waves done reading z

  // ---- epilogue: pack bf16 pairs, swizzled LDS transpose (verified) ----
  #pragma unroll
  for (int mt = 0; mt < 4; ++mt)
    #pragma unroll
    for (int cti = 0; cti < 2; ++cti)
      #pragma unroll
      for (int rr = 0; rr < 4; ++rr) {
        unsigned ub = pkbf(acc[mt][cti][rr], 0.f) & 0xffffu;
        unsigned pb = (unsigned)__shfl_xor((int)ub, 1);
        if (!(l & 1)) {
          int orow = mt * 16 + ((l >> 4) << 2) + rr;
          int colp = (L * 128 + (ctp * 2 + cti) * 16 + (l & 15)) >> 1;
          int c = colp >> 2;
          int ec = ((c ^ orow) & 7) | (c & 24);
          *(unsigned*)(smem + orow * 512 + ec * 16 + (colp & 3) * 4) = ub | (pb << 16);
        }
      }
  __syncthreads();
  #pragma unroll
  for (int p = 0; p < 4; ++p) {
    int e = p * 512 + t; int rr = e >> 5, v4 = e & 31;
    int ec = ((v4 ^ rr) & 7) | (v4 & 24);
    uint4 val = *(const uint4*)(smem + rr * 512 + ec * 16);
    if (row0 + rr < N) ((uint4*)outp)[(size_t)(row0 + rr) * 32 + v4] = val;
  }
}

// ---------------- K4: BN finalize -> scale/shift (R5 verbatim) ----------------
__global__ void k_bnfin(const float* __restrict__ g1, const float* __restrict__ b1,
                        const float* __restrict__ g2, const float* __restrict__ b2,
                        float* __restrict__ ws, int N) {
  int c = threadIdx.x;  // 256
  float s = 0.f, q = 0.f;
  for (int m = 0; m < 32; ++m) { s += ws[STAT_OFF + m * 512 + c]; q += ws[STAT_OFF + m * 512 + 256 + c]; }
  float inv = 1.f / (float)N;
  float mu = s * inv;
  float var = fmaxf(q * inv - mu * mu, 0.f);
  int lyr = c >> 7, cc = c & 127;
  float ga = lyr ? g2[cc] : g1[cc];
  float be = lyr ? b2[cc] : b1[cc];
  float sc = ga * rsqrtf(var + EPS);
  ws[SCALE_OFF + c] = sc;
  ws[SHIFT_OFF + c] = be - mu * sc;
}

// ---- k_fc staging (R8-verified: single x read per row, reused for both halves) ----
__device__ __forceinline__ void load_fc(const unsigned* __restrict__ hp, const float* __restrict__ x,
    int row, int g, uint4* hv, float4* xv, int N) {
  if (row < N) {
    const uint4* hs = (const uint4*)((const char*)hp + (size_t)row * 512);
    hv[0] = hs[2 * g]; hv[1] = hs[2 * g + 1]; hv[2] = hs[2 * g + 16]; hv[3] = hs[2 * g + 17];
    const float4* xs = (const float4*)(x + (size_t)row * 128 + g * 16);
    xv[0] = xs[0]; xv[1] = xs[1]; xv[2] = xs[2]; xv[3] = xs[3];
  } else {
    #pragma unroll
    for (int i = 0; i < 4; ++i) { hv[i] = (uint4){0u,0u,0u,0u}; xv[i] = (float4){0.f,0.f,0.f,0.f}; }
  }
}

__device__ __forceinline__ void proc_fc(const uint4* hv, const float4* xv, const float* scsh,
    int r, int g, char* z) {
  const unsigned* hu = (const unsigned*)hv;
  const float* xf = (const float*)xv;
  #pragma unroll
  for (int hh = 0; hh < 2; ++hh) {
    #pragma unroll
    for (int d = 0; d < 2; ++d) {
      uint4 wq;
      unsigned* wu = (unsigned*)&wq;
      #pragma unroll
      for (int jj = 0; jj < 4; ++jj) {
        int xi = d * 8 + 2 * jj;
        int k = g * 16 + hh * 128 + d * 8 + 2 * jj;
        unsigned hraw = hu[hh * 8 + d * 4 + jj];
        float lo = bf2f(hraw & 0xffffu) * scsh[k]     + scsh[256 + k]     + xf[xi];
        float hi = bf2f(hraw >> 16)     * scsh[k + 1] + scsh[256 + k + 1] + xf[xi + 1];
        wu[jj] = pkbf(fmaxf(lo, 0.f), fmaxf(hi, 0.f));
      }
      int c = 2 * g + hh * 16 + d;          // chunk index 0..31
      int kb = c >> 2, hf = c & 3;
      int slot = (hf << 3) | ((kb ^ r ^ hf) & 7);
      *(uint4*)(z + r * 512 + slot * 16) = wq;
    }
  }
}

// ---------------- K5: BN+res+relu + MFMA fc GEMM (R8 staging, no pipeline) + B-in-regs + swizzle ----------------
__global__ __launch_bounds__(512) void k_fc(
    const float* __restrict__ x, const float* __restrict__ fcb,
    float* __restrict__ ws, float* __restrict__ out, int N, int nT) {
  __shared__ __align__(16) char smem[32768];
  __shared__ float scsh[512];
  int t = threadIdx.x, l = t & 63, w = t >> 6;
  int tile = xcd_tile(blockIdx.x, nT);
  int row0 = tile * 64;
  const unsigned* hp = (const unsigned*)out;
  const unsigned short* Fpk = (const unsigned short*)(ws + FCPK_OFF);
  int half = l >> 4;

  // ---- B-frag preload: 8 loads, L2-hot, drained by the staging barrier ----
  bf16x8 Bfr[8];
  #pragma unroll
  for (int kb = 0; kb < 8; ++kb)
    Bfr[kb] = *(const bf16x8*)(Fpk + ((w * 8 + kb) * 64 + l) * 8);

  scsh[t] = ws[SCALE_OFF + t];
  int rg = t >> 3, g = t & 7;
  uint4 hv[4]; float4 xv[4];
  load_fc(hp, x, row0 + rg, g, hv, xv, N);
  float bias = fcb[(w << 4) + (l & 15)];
  __syncthreads();                 // scsh ready
  proc_fc(hv, xv, scsh, rg, g, smem);
  __syncthreads();

  // ---- MFMA K=256: pure LDS + registers ----
  f32x4 acc[4];
  #pragma unroll
  for (int mt = 0; mt < 4; ++mt) acc[mt] = (f32x4){0.f, 0.f, 0.f, 0.f};
  #pragma unroll
  for (int kb = 0; kb < 8; ++kb) {
    #pragma unroll
    for (int mt = 0; mt < 4; ++mt) {
      int rr = mt * 16 + (l & 15);
      int slot = ((kb ^ rr ^ half) & 7) | (half << 3);
      bf16x8 af = *(const bf16x8*)(smem + rr * 512 + slot * 16);
      acc[mt] = __builtin_amdgcn_mfma_f32_16x16x32_bf16(af, Bfr[kb], acc[mt], 0, 0, 0);
    }
  }
  __syncthreads();   // done reading z

  // ---- epilogue: bias + relu, swizzled f32 transpose ----
  #pragma unroll
  for (int mt = 0; mt < 4; ++mt)
    #pragma unroll
    for (int rr = 0; rr < 4; ++rr) {
      int orow = mt * 16 + ((l >> 4) << 2) + rr;
      int col = (w << 4) + (l & 15);
      int ch = col >> 2;
      int cs = ((ch ^ orow) & 7) | (ch & 24);
      *(float*)(smem + orow * 512 + cs * 16 + (col & 3) * 4) = fmaxf(acc[mt][rr] + bias, 0.f);
    }
  __syncthreads();
  #pragma unroll
  for (int p = 0; p < 4; ++p) {
    int e = p * 512 + t; int rr = e >> 5, v4 = e & 31;
    int cs = ((v4 ^ rr) & 7) | (v4 & 24);
    float4 val = *(const float4*)(smem + rr * 512 + cs * 16);
    if (row0 + rr < N) ((float4*)out)[(size_t)(row0 + rr) * 32 + v4] = val;
  }
}

extern "C" void kernel_launch(void* const* d_in, const int* in_sizes, int n_in,
                              void* d_out, int out_size, void* d_ws, size_t ws_size,
                              hipStream_t stream) {
  const float* x    = (const float*)d_in[0];
  const float* rdf  = (const float*)d_in[1];
  const float* bdf  = (const float*)d_in[2];
  const int*   aidx = (const int*)d_in[3];
  const int*   eidx = (const int*)d_in[4];
  const float* rdfW = (const float*)d_in[5];
  const float* rdfG = (const float*)d_in[7];
  const float* rdfBe= (const float*)d_in[8];
  const float* bdfW = (const float*)d_in[9];
  const float* bdfG = (const float*)d_in[11];
  const float* bdfBe= (const float*)d_in[12];
  const float* fcW  = (const float*)d_in[13];
  const float* fcB  = (const float*)d_in[14];
  float* out = (float*)d_out;
  float* ws  = (float*)d_ws;
  int N = in_sizes[0] / 128;
  int nT = (N + 63) / 64;

  hipMemsetAsync(d_ws, 0, (size_t)ZERO_WORDS * 4, stream);
  k_prep<<<160, 512, 0, stream>>>(rdfW, bdfW, fcW, ws);
  k_seg<<<(N + 255) / 256, 256, 0, stream>>>(x, aidx, eidx, ws, N);
  k_fin<<<2048, 256, 0, stream>>>(ws);
  k_gemm<<<nT, 512, 0, stream>>>(rdf, bdf, aidx, eidx, ws, (unsigned*)d_out, N, nT);
  k_bnfin<<<1, 256, 0, stream>>>(rdfG, rdfBe, bdfG, bdfBe, ws, N);
  k_fc<<<nT, 512, 0, stream>>>(x, fcB, ws, out, N, nT);
}